// Round 5
// baseline (458.777 us; speedup 1.0000x reference)
//
#include <hip/hip_runtime.h>
#include <hip/hip_cooperative_groups.h>
#include <stdint.h>

namespace cg = cooperative_groups;

// ---------------------------------------------------------------------------
// GroupAttentionLayer: RF=16,STRIDE=16 windows tile the image exactly =>
//   yout = leaky(Q K^T / 16) V  (full dense attention per batch), then BN +
//   spatial softmax (mu/beta cancel; only a_c = g1/sqrt(var+eps) survives).
// B=4, P=4096 px/batch (T=16384 rows), C=256. Inputs fp32, OUTPUT fp32.
// R7:  k_attn operands FRAGMENT-MAJOR in global (lane-contiguous 1KB loads).
// R8:  BN stats fused into GEMM epilogue; frag-major fp32 YQK; setprio (+7%).
// R9:  launch fusion; coefs inline in k_bn; 1/16 folded into Q coefs.
// R10: q-tile 128 -> SLOWER (latency-bound at 1 blk/CU). REVERTED.
// R11: Gram-matrix analytic stats -> REGRESSION +26us (k_gram scalar LDS
//      transpose + k_coef2 re-reads). REVERTED to R2 pipeline.
// R12 (this round), on the R2 base:
//   * k_red FUSED into k_attn (split-K last-block reduction): both halves
//     store partials; counter atomicAdd; second finisher combines own acc2 +
//     other half's P from LLC, writes yout IN PLACE over P0, LDS-reduces BN
//     stats (1 f64 atomic pair/channel). Kills a 50MB pass + a dispatch.
//   * soft1+soft2 FUSED via cooperative grid.sync(): 64 exp values held in
//     registers across the sync (fully unrolled), then scaled by 1/sum.
//     Kills a 17MB yout re-read + a dispatch.  Pipeline = 5 dispatches.
//   Qf/Kf[((g*16+ks)*64+lane)*8+j] : row=g*32+(lane&31), ch=ks*16+(lane>>5)*8+j
//   Vf[((gc*256+kp)*64+lane)*8+j]  : ch=(gc&7)*32+(lane&31), key=kp*16+(lane>>5)*8+j
// ---------------------------------------------------------------------------

typedef __attribute__((ext_vector_type(8)))  short short8;   // 8 x bf16
typedef __attribute__((ext_vector_type(4)))  float f32x4;    // 16x16 acc
typedef __attribute__((ext_vector_type(16))) float f32x16;   // 32x32 acc
typedef __attribute__((ext_vector_type(4)))  unsigned short ushort4v;

#define ALPHA 0.3f
#define EPS   1e-3
#define NTOT  16384.0

__device__ __forceinline__ unsigned short f2bf(float f){
  unsigned u = __float_as_uint(f);
  u += 0x7FFFu + ((u>>16)&1u);          // RNE
  return (unsigned short)(u>>16);
}
__device__ __forceinline__ float lrelu(float x){ return fmaxf(x, ALPHA*x); }

// ------------------------------------------------- prep: cvt + wtrans + zero
// blocks [0,4096): X fp32->bf16.  blocks [4096,4864): W transpose->bf16;
// zero range covers st (4096 f32) + sums (1024 f32) + cnt (256 u32) = 5376.
__global__ __launch_bounds__(256)
void k_prep(const float* __restrict__ X,
            const float* __restrict__ Wq,
            const float* __restrict__ Wk,
            const float* __restrict__ Wv,
            unsigned short* __restrict__ Xb,
            unsigned short* __restrict__ Wt,
            float* __restrict__ zws){
  int blk = blockIdx.x, tid = threadIdx.x;
  if (blk < 4096){
    int i = (blk*256 + tid)*4;
    float4 v = *(const float4*)(X + i);
    ushort4v o; o.x = f2bf(v.x); o.y = f2bf(v.y); o.z = f2bf(v.z); o.w = f2bf(v.w);
    *(ushort4v*)(Xb + i) = o;
  } else {
    int o = (blk - 4096)*256 + tid;              // 0 .. 196607
    int p = o >> 16, rem = o & 65535;
    int j = rem >> 8, c = rem & 255;
    const float* W = (p==0) ? Wq : ((p==1) ? Wk : Wv);
    Wt[o] = f2bf(W[c*256 + j]);
    if (o < 5376) zws[o] = 0.f;                  // st + sums + cnt
  }
}

// --------------------------------------------------------------- QKV GEMM
// Y[t][n] = sum_c Xb[t][c] * Wt[n][c],  t<16384, n<768.
// Q/K planes (nb<8) written fragment-major fp32 into YQK; V (nb>=8) row-major
// into Yv. BN stats (sum, sumsq per channel) fused into the epilogue.
__global__ __launch_bounds__(256)
void k_qkv_gemm(const unsigned short* __restrict__ X,
                const unsigned short* __restrict__ Wt,
                float* __restrict__ YQK, float* __restrict__ Yv,
                double* __restrict__ st){
  __shared__ __align__(16) unsigned short At[64*264];
  __shared__ __align__(16) unsigned short Bt[64*264];
  int tid = threadIdx.x;
  int mb = blockIdx.x, nb = blockIdx.y;
#pragma unroll
  for (int it = 0; it < 8; ++it){
    int s = it*256 + tid;
    int row = s >> 5, ch = s & 31;
    uint4 a = *(const uint4*)(X  + ((size_t)(mb*64 + row))*256 + ch*8);
    uint4 b = *(const uint4*)(Wt + ((size_t)(nb*64 + row))*256 + ch*8);
    *(uint4*)(At + row*264 + ch*8) = a;
    *(uint4*)(Bt + row*264 + ch*8) = b;
  }
  __syncthreads();
  int lane = tid & 63, wv = tid >> 6;
  int ln15 = lane & 15, quad = lane >> 4;
  int rw = (wv & 1)*32, cw = (wv >> 1)*32;     // 2x2 waves, 32x32 each
  f32x4 acc[2][2] = {};
#pragma unroll
  for (int ks = 0; ks < 8; ++ks){
    short8 afr[2], bfr[2];
#pragma unroll
    for (int mt = 0; mt < 2; ++mt){
      int r = rw + mt*16 + ln15;
      afr[mt] = *(const short8*)(At + r*264 + (ks*4+quad)*8);
    }
#pragma unroll
    for (int nt = 0; nt < 2; ++nt){
      int r = cw + nt*16 + ln15;
      bfr[nt] = *(const short8*)(Bt + r*264 + (ks*4+quad)*8);
    }
#pragma unroll
    for (int mt = 0; mt < 2; ++mt)
#pragma unroll
      for (int nt = 0; nt < 2; ++nt)
        acc[mt][nt] = __builtin_amdgcn_mfma_f32_16x16x32_bf16(afr[mt], bfr[nt], acc[mt][nt], 0,0,0);
  }
  // ---- per-lane column partials for BN stats (raw Y values)
  float ps[2] = {0.f, 0.f}, pq[2] = {0.f, 0.f};
#pragma unroll
  for (int mt = 0; mt < 2; ++mt)
#pragma unroll
    for (int nt = 0; nt < 2; ++nt)
#pragma unroll
      for (int r = 0; r < 4; ++r){
        float v = acc[mt][nt][r];
        ps[nt] += v; pq[nt] += v*v;
      }
  // ---- C-store
  if (nb < 8){
    int proj = nb >> 2;
    float* base = YQK + (size_t)proj*(16384*256);
    int l5c = ln15 >> 3, j = ln15 & 7;
#pragma unroll
    for (int mt = 0; mt < 2; ++mt){
      int g = (mb*64 + rw + mt*16) >> 5;
      int l31r0 = ((rw + mt*16) & 31) + quad*4;
#pragma unroll
      for (int nt = 0; nt < 2; ++nt){
        int ks2 = ((nb & 3)*64 + cw + nt*16) >> 4;
#pragma unroll
        for (int r = 0; r < 4; ++r){
          size_t chunk = (size_t)((g*16 + ks2)*64 + l5c*32 + l31r0 + r);
          base[chunk*8 + j] = acc[mt][nt][r];
        }
      }
    }
  } else {
    int vc0 = (nb - 8)*64 + cw;
#pragma unroll
    for (int mt = 0; mt < 2; ++mt)
#pragma unroll
      for (int nt = 0; nt < 2; ++nt)
#pragma unroll
        for (int r = 0; r < 4; ++r){
          int row = mb*64 + rw + mt*16 + quad*4 + r;
          Yv[(size_t)row*256 + vc0 + nt*16 + ln15] = acc[mt][nt][r];
        }
  }
  // ---- stats reduce: LDS (reuse At) then one f64 atomic pair per channel
  __syncthreads();
  float* red = (float*)At;               // [0..64) sum, [64..128) sumsq
  if (tid < 128) red[tid] = 0.f;
  __syncthreads();
#pragma unroll
  for (int nt = 0; nt < 2; ++nt){
    int colL = cw + nt*16 + ln15;        // 0..63
    atomicAdd(&red[colL],      ps[nt]);
    atomicAdd(&red[64 + colL], pq[nt]);
  }
  __syncthreads();
  if (tid < 64){
    int cc = nb*64 + tid;                // global channel 0..767
    atomicAdd(&st[cc],       (double)red[tid]);
    atomicAdd(&st[768 + cc], (double)red[64 + tid]);
  }
}

// ------------------------------------------------- BN+leaky: Q,K frag stream
// + V transpose, one dispatch. Coefs computed inline from st.
// Q coefs carry an extra 1/16 (score scale folded in; exact exponent shift).
__global__ __launch_bounds__(256)
void k_bn(const float* __restrict__ YQK, const float* __restrict__ Yv,
          const double* __restrict__ st,
          const float* __restrict__ gq, const float* __restrict__ bq,
          const float* __restrict__ gk, const float* __restrict__ bk,
          const float* __restrict__ gv, const float* __restrict__ bv,
          unsigned short* __restrict__ Qf, unsigned short* __restrict__ Kf,
          unsigned short* __restrict__ Vf){
  __shared__ float sc_s[256], sh_s[256];
  __shared__ unsigned short tile[64][66];
  int tid = threadIdx.x;
  int blk = blockIdx.x;
  if (blk < 4096){
    int proj = blk >> 11;                        // 2048 blocks per proj (0=Q,1=K)
    {
      int c = tid;
      int cc = proj*256 + c;
      double mu  = st[cc]     * (1.0/NTOT);
      double var = st[768+cc] * (1.0/NTOT) - mu*mu;
      double g = proj ? (double)gk[c] : (double)gq[c];
      double b = proj ? (double)bk[c] : (double)bq[c];
      double a = g / sqrt(var + EPS);
      float f = proj ? 1.f : 0.0625f;            // fold 1/16 into Q
      sc_s[c] = (float)a * f;
      sh_s[c] = (float)(b - mu*a) * f;
    }
    __syncthreads();
    int oc = blk*256 + tid;                      // chunk of 8 values
    int rest = oc & 524287;
    int ks = (rest >> 6) & 15, l5c = (rest >> 5) & 1;
    int ch0 = ks*16 + l5c*8;
    const float* src = YQK + (size_t)oc*8;
    float4 v0 = *(const float4*)(src);
    float4 v1 = *(const float4*)(src + 4);
    const float* sc = sc_s + ch0;
    const float* sh = sh_s + ch0;
    unsigned short r[8];
    r[0]=f2bf(lrelu(v0.x*sc[0]+sh[0])); r[1]=f2bf(lrelu(v0.y*sc[1]+sh[1]));
    r[2]=f2bf(lrelu(v0.z*sc[2]+sh[2])); r[3]=f2bf(lrelu(v0.w*sc[3]+sh[3]));
    r[4]=f2bf(lrelu(v1.x*sc[4]+sh[4])); r[5]=f2bf(lrelu(v1.y*sc[5]+sh[5]));
    r[6]=f2bf(lrelu(v1.z*sc[6]+sh[6])); r[7]=f2bf(lrelu(v1.w*sc[7]+sh[7]));
    uint4 u;
    u.x = (unsigned)r[0] | ((unsigned)r[1]<<16);
    u.y = (unsigned)r[2] | ((unsigned)r[3]<<16);
    u.z = (unsigned)r[4] | ((unsigned)r[5]<<16);
    u.w = (unsigned)r[6] | ((unsigned)r[7]<<16);
    *(uint4*)((proj ? Kf : Qf) + (size_t)rest*8) = u;
  } else {
    int b2 = blk - 4096;
    int pt = b2 & 63, ct = (b2 >> 6) & 3, b = b2 >> 8;
    if (tid < 64){
      int c = ct*64 + tid;
      int cc = 512 + c;
      double mu  = st[cc]     * (1.0/NTOT);
      double var = st[768+cc] * (1.0/NTOT) - mu*mu;
      double a = (double)gv[c] / sqrt(var + EPS);
      sc_s[tid] = (float)a;
      sh_s[tid] = (float)((double)bv[c] - mu*a);
    }
    __syncthreads();
    int cl = tid & 63, rq = tid >> 6;
    int c  = ct*64 + cl;
    float sc = sc_s[cl], sh = sh_s[cl];
#pragma unroll 4
    for (int k = 0; k < 16; ++k){
      int r = k*4 + rq;
      size_t t = (size_t)b*4096 + pt*64 + r;
      float v = Yv[t*256 + c];
      tile[r][cl] = f2bf(lrelu(v*sc + sh));
    }
    __syncthreads();
#pragma unroll
    for (int it = 0; it < 2; ++it){
      int m = it*256 + tid;                      // 512 chunks of 8 keys
      int c2 = m >> 3, kg = m & 7;
      int ch = ct*64 + c2;
      int gc = b*8 + (ch >> 5), l31c = ch & 31;
      int kp = pt*4 + (kg >> 1), l5k = kg & 1;
      unsigned short r0 = tile[kg*8+0][c2], r1 = tile[kg*8+1][c2];
      unsigned short r2 = tile[kg*8+2][c2], r3 = tile[kg*8+3][c2];
      unsigned short r4 = tile[kg*8+4][c2], r5 = tile[kg*8+5][c2];
      unsigned short r6 = tile[kg*8+6][c2], r7 = tile[kg*8+7][c2];
      uint4 u;
      u.x = (unsigned)r0 | ((unsigned)r1<<16);
      u.y = (unsigned)r2 | ((unsigned)r3<<16);
      u.z = (unsigned)r4 | ((unsigned)r5<<16);
      u.w = (unsigned)r6 | ((unsigned)r7<<16);
      *(uint4*)(Vf + ((size_t)((gc*256 + kp)*64 + l5k*32 + l31c))*8) = u;
    }
  }
}

// --------------------------------------------------------------- attention
// R2 structure (best measured): 512 blocks x 512 threads, q-tile 64.
// blk&7 = (b,half) -> XCD-pinned. 8 iters of BK=256, 2 barriers/iter.
// setprio(1) wraps MFMA phases. R12: split-K last-block reduction fused --
// the second (b,qt) finisher folds P0+P1 -> yout (in place over P0) and
// accumulates BN stats; k_red eliminated.
__global__ __launch_bounds__(512, 4)
void k_attn(const unsigned short* __restrict__ Qf,
            const unsigned short* __restrict__ Kf,
            const unsigned short* __restrict__ Vf,
            float* __restrict__ P0, float* __restrict__ P1,
            unsigned* __restrict__ cnt, double* __restrict__ st){
  __shared__ __align__(16) unsigned short Ql[64*256];   // frag-major Q tile
  __shared__ __align__(16) unsigned short Sl[64*264];   // [q][key] padded
  int tid = threadIdx.x;
  int blk = blockIdx.x;
  int qt = blk >> 3, combo = blk & 7;
  int b = combo >> 1, half = combo & 1;
  int q0 = qt*64;
  int lane = tid & 63, w = tid >> 6;
  int l31 = lane & 31, l5 = lane >> 5;
  float* P = half ? P1 : P0;

  int gq0 = b*128 + qt*2;
  {
    const uint4* src = (const uint4*)(Qf + (size_t)gq0*8192);
    uint4* dst = (uint4*)Ql;
#pragma unroll
    for (int it = 0; it < 4; ++it) dst[it*512 + tid] = src[it*512 + tid];
  }
  __syncthreads();

  f32x16 acc2[2] = {};
  int gk0 = b*128 + half*64 + w;
  const unsigned short* kb = Kf + (size_t)gk0*8192 + lane*8;
  const unsigned short* vb = Vf + ((size_t)((b*8 + w)*256 + half*128))*512 + lane*8;
  const unsigned short* qa0 = Ql + lane*8;
  const unsigned short* qa1 = Ql + 16*512 + lane*8;

  for (int kt = 0; kt < 8; ++kt){
    f32x16 a1[2] = {};
    const unsigned short* kbt = kb + (size_t)kt*8*8192;
    __builtin_amdgcn_s_setprio(1);
#pragma unroll
    for (int ks = 0; ks < 16; ++ks){
      short8 kf = *(const short8*)(kbt + ks*512);
      short8 q0v = *(const short8*)(qa0 + ks*512);
      short8 q1v = *(const short8*)(qa1 + ks*512);
      a1[0] = __builtin_amdgcn_mfma_f32_32x32x16_bf16(q0v, kf, a1[0], 0, 0, 0);
      a1[1] = __builtin_amdgcn_mfma_f32_32x32x16_bf16(q1v, kf, a1[1], 0, 0, 0);
    }
    __builtin_amdgcn_s_setprio(0);
    __syncthreads();     // B0
#pragma unroll
    for (int reg = 0; reg < 16; ++reg){
      int rloc = (reg & 3) + 8*(reg >> 2) + 4*l5;
      float x0 = a1[0][reg], x1 = a1[1][reg];
      Sl[rloc*264 + w*32 + l31]        = f2bf(fmaxf(x0, 0.3f*x0));
      Sl[(32 + rloc)*264 + w*32 + l31] = f2bf(fmaxf(x1, 0.3f*x1));
    }
    __syncthreads();     // B1
    const unsigned short* vbt = vb + (size_t)kt*16*512;
    __builtin_amdgcn_s_setprio(1);
#pragma unroll
    for (int kk = 0; kk < 16; ++kk){
      short8 vf = *(const short8*)(vbt + kk*512);
      short8 s0 = *(const short8*)(Sl + (     l31)*264 + kk*16 + l5*8);
      short8 s1 = *(const short8*)(Sl + (32 + l31)*264 + kk*16 + l5*8);
      acc2[0] = __builtin_amdgcn_mfma_f32_32x32x16_bf16(s0, vf, acc2[0], 0, 0, 0);
      acc2[1] = __builtin_amdgcn_mfma_f32_32x32x16_bf16(s1, vf, acc2[1], 0, 0, 0);
    }
    __builtin_amdgcn_s_setprio(0);
  }
  // ---- store own partial
#pragma unroll
  for (int c = 0; c < 2; ++c)
#pragma unroll
    for (int reg = 0; reg < 16; ++reg){
      int row = q0 + c*32 + (reg & 3) + 8*(reg >> 2) + 4*l5;
      P[((size_t)b*4096 + row)*256 + w*32 + l31] = acc2[c][reg];
    }
  // ---- split-K last-block reduction (release: fence, then counter)
  __threadfence();
  __shared__ unsigned sOld;
  __syncthreads();
  if (tid == 0) sOld = atomicAdd(&cnt[(b<<6) + qt], 1u);
  __syncthreads();
  if (sOld == 0) return;            // first finisher exits
  __threadfence();                  // acquire
  const float* Po = half ? P0 : P1; // the other half's partials
  double sum = 0.0, sq = 0.0;
#pragma unroll
  for (int c = 0; c < 2; ++c)
#pragma unroll
    for (int reg = 0; reg < 16; ++reg){
      int row = q0 + c*32 + (reg & 3) + 8*(reg >> 2) + 4*l5;
      size_t idx = ((size_t)b*4096 + row)*256 + w*32 + l31;
      float v = acc2[c][reg] + Po[idx];
      P0[idx] = v;                  // yout in place
      sum += v; sq += (double)v*v;
    }
  double* redS = (double*)Sl;       // reuse: all threads past last Sl read
  redS[tid] = sum; redS[512 + tid] = sq;
  __syncthreads();
  if ((tid & 32) == 0){
    int c = ((tid >> 6) << 5) + (tid & 31);   // channel 0..255
    atomicAdd(&st[1536 + c], redS[tid] + redS[tid + 32]);
    atomicAdd(&st[1792 + c], redS[512 + tid] + redS[512 + tid + 32]);
  }
}

// ------------------------------------------- fused softmax (cooperative)
// BN => args are z-scores: shift by a*mu only. Pass 1 computes exp + partial
// sums (held in registers), grid.sync, pass 2 scales by 1/sum.
__global__ __launch_bounds__(256)
void k_soft(const float* __restrict__ yout, const double* __restrict__ st,
            const float* __restrict__ g1, float* __restrict__ sums,
            float* __restrict__ out){
  __shared__ float red[256];
  __shared__ float sA[64], sK[64], sR[64];
  int tid = threadIdx.x;
  int chunk = blockIdx.x, ct = blockIdx.y, b = blockIdx.z;
  int cl = tid & 63, pg = tid >> 6;
  int c = ct*64 + cl;
  if (tid < 64){
    int cc = ct*64 + tid;
    double mu  = st[1536 + cc]*(1.0/NTOT);
    double var = st[1792 + cc]*(1.0/NTOT) - mu*mu;
    double a = g1[cc] / sqrt(var + EPS);
    sA[tid] = (float)a;
    sK[tid] = (float)(a*mu);
  }
  __syncthreads();
  float a = sA[cl], K = sK[cl];
  float e[64];
  float s = 0.f;
  const float* base = yout + ((size_t)b*4096 + chunk*256)*256 + c;
#pragma unroll
  for (int k = 0; k < 64; ++k){
    float v = base[(size_t)(pg + k*4)*256];
    e[k] = __expf(v*a - K);
    s += e[k];
  }
  red[tid] = s;
  __syncthreads();
  if (tid < 64){
    float tot = red[tid] + red[64+tid] + red[128+tid] + red[192+tid];
    atomicAdd(&sums[b*256 + ct*64 + tid], tot);
  }
  cg::this_grid().sync();
  if (tid < 64) sR[tid] = 1.f / sums[b*256 + ct*64 + tid];
  __syncthreads();
  float rl = sR[cl];
  float* obase = out + ((size_t)b*4096 + chunk*256)*256 + c;
#pragma unroll
  for (int k = 0; k < 64; ++k)
    obase[(size_t)(pg + k*4)*256] = e[k] * rl;
}

// ---------------------------------------------------------------------------
extern "C" void kernel_launch(void* const* d_in, const int* in_sizes, int n_in,
                              void* d_out, int out_size, void* d_ws, size_t ws_size,
                              hipStream_t stream){
  (void)in_sizes; (void)n_in; (void)out_size; (void)ws_size;
  const float* X  = (const float*)d_in[0];
  const float* Wq = (const float*)d_in[1];
  const float* gq = (const float*)d_in[2];
  const float* bq = (const float*)d_in[3];
  const float* Wk = (const float*)d_in[4];
  const float* gk = (const float*)d_in[5];
  const float* bk = (const float*)d_in[6];
  const float* Wv = (const float*)d_in[7];
  const float* gv = (const float*)d_in[8];
  const float* bv = (const float*)d_in[9];
  const float* g1 = (const float*)d_in[10];
  // d_in[11] = b1: cancels inside the spatial softmax

  char* ws = (char*)d_ws;
  double*         st   = (double*)ws;                        // 2048 f64 (16KB)
  float*          sums = (float*)(ws + 16384);               // 4KB
  unsigned*       cnt  = (unsigned*)(ws + 20480);            // 256 u32 (1KB)
  unsigned short* Wt   = (unsigned short*)(ws + 26624);      // 768x256 bf16
  unsigned short* Xb   = (unsigned short*)(ws + 419840);     // 16384x256 bf16
  float*          YQK  = (float*)(ws + 8808448);             // 2x16384x256 f32 (frag-major)
  float*          Yv   = (float*)(ws + 42362880);            // 16384x256 f32 row-major
  unsigned short* Kf   = (unsigned short*)(ws + 59140096);   // frag-major 8MB
  unsigned short* Vf   = (unsigned short*)(ws + 67528704);   // frag-major 8MB
  // overlays: Qf on Xb (dead after GEMM); P0|P1 on YQK (dead after bn);
  // yout = P0 in place (finisher overwrites consumed partials)
  unsigned short* Qf   = Xb;
  float*          P0   = YQK;
  float*          P1   = (float*)((char*)YQK + 16777216);
  float*          yo   = P0;
  float*          outp = (float*)d_out;

  k_prep    <<<4864, 256, 0, stream>>>(X, Wq, Wk, Wv, Xb, Wt, (float*)st);
  k_qkv_gemm<<<dim3(256,12), 256, 0, stream>>>(Xb, Wt, YQK, Yv, st);
  k_bn      <<<5120, 256, 0, stream>>>(YQK, Yv, st, gq, bq, gk, bk, gv, bv, Qf, Kf, Vf);
  k_attn    <<<512, 512, 0, stream>>>(Qf, Kf, Vf, P0, P1, cnt, st);
  {
    void* sargs[5];
    sargs[0] = (void*)&yo;
    sargs[1] = (void*)&st;
    sargs[2] = (void*)&g1;
    sargs[3] = (void*)&sums;
    sargs[4] = (void*)&outp;
    hipLaunchCooperativeKernel((const void*)k_soft, dim3(16,4,4), dim3(256,1,1),
                               sargs, 0, stream);
  }
}

// Round 6
// 356.773 us; speedup vs baseline: 1.2859x; 1.2859x over previous
//
#include <hip/hip_runtime.h>
#include <hip/hip_cooperative_groups.h>
#include <stdint.h>

namespace cg = cooperative_groups;

// ---------------------------------------------------------------------------
// GroupAttentionLayer: RF=16,STRIDE=16 windows tile the image exactly =>
//   yout = leaky(Q K^T / 16) V  (full dense attention per batch), then BN +
//   spatial softmax (mu/beta cancel; only a_c = g1/sqrt(var+eps) survives).
// B=4, P=4096 px/batch (T=16384 rows), C=256. Inputs fp32, OUTPUT fp32.
// R7:  k_attn operands FRAGMENT-MAJOR in global (lane-contiguous 1KB loads).
// R8:  BN stats fused into GEMM epilogue; frag-major fp32 YQK; setprio (+7%).
// R9:  launch fusion; coefs inline in k_bn; 1/16 folded into Q coefs.
// R10: q-tile 128 -> SLOWER (latency-bound at 1 blk/CU). REVERTED.
// R11: Gram-matrix analytic stats -> REGRESSION (+26us). REVERTED.
// R12: split-K fusion of k_red into k_attn -> CATASTROPHIC (75->278us):
//      per-block device __threadfence() flushes the XCD L2, destroying K/V
//      residency (FETCH 16.4->24.6MB). REVERTED. Lesson: no hand-rolled
//      cross-XCD producer/consumer; only grid.sync-mediated phases.
// R13 (this round): k_attn = exact R2 structure (best measured 74.9us).
//      Tail fused the SAFE way: ONE cooperative kernel k_rs replaces
//      k_red+soft1+soft2. The 32 per-thread values live in registers across
//      two grid.sync()s: phase1 reads P0+P1 + BN-stat atomics; phase2 coefs
//      + exp + per-channel sum atomics; phase3 scale + write out. Saves the
//      yout write (17MB) + two re-reads (34MB) + 2 dispatches.
//   Qf/Kf[((g*16+ks)*64+lane)*8+j] : row=g*32+(lane&31), ch=ks*16+(lane>>5)*8+j
//   Vf[((gc*256+kp)*64+lane)*8+j]  : ch=(gc&7)*32+(lane&31), key=kp*16+(lane>>5)*8+j
// ---------------------------------------------------------------------------

typedef __attribute__((ext_vector_type(8)))  short short8;   // 8 x bf16
typedef __attribute__((ext_vector_type(4)))  float f32x4;    // 16x16 acc
typedef __attribute__((ext_vector_type(16))) float f32x16;   // 32x32 acc
typedef __attribute__((ext_vector_type(4)))  unsigned short ushort4v;

#define ALPHA 0.3f
#define EPS   1e-3
#define NTOT  16384.0

__device__ __forceinline__ unsigned short f2bf(float f){
  unsigned u = __float_as_uint(f);
  u += 0x7FFFu + ((u>>16)&1u);          // RNE
  return (unsigned short)(u>>16);
}
__device__ __forceinline__ float lrelu(float x){ return fmaxf(x, ALPHA*x); }

// ------------------------------------------------- prep: cvt + wtrans + zero
// blocks [0,4096): X fp32->bf16.  blocks [4096,4864): W transpose->bf16;
// zero range covers st (4096 f32) + sums (1024 f32) = 5120 f32.
__global__ __launch_bounds__(256)
void k_prep(const float* __restrict__ X,
            const float* __restrict__ Wq,
            const float* __restrict__ Wk,
            const float* __restrict__ Wv,
            unsigned short* __restrict__ Xb,
            unsigned short* __restrict__ Wt,
            float* __restrict__ zws){
  int blk = blockIdx.x, tid = threadIdx.x;
  if (blk < 4096){
    int i = (blk*256 + tid)*4;
    float4 v = *(const float4*)(X + i);
    ushort4v o; o.x = f2bf(v.x); o.y = f2bf(v.y); o.z = f2bf(v.z); o.w = f2bf(v.w);
    *(ushort4v*)(Xb + i) = o;
  } else {
    int o = (blk - 4096)*256 + tid;              // 0 .. 196607
    int p = o >> 16, rem = o & 65535;
    int j = rem >> 8, c = rem & 255;
    const float* W = (p==0) ? Wq : ((p==1) ? Wk : Wv);
    Wt[o] = f2bf(W[c*256 + j]);
    if (o < 5120) zws[o] = 0.f;                  // st + sums
  }
}

// --------------------------------------------------------------- QKV GEMM
// Y[t][n] = sum_c Xb[t][c] * Wt[n][c],  t<16384, n<768.
// Q/K planes (nb<8) written fragment-major fp32 into YQK; V (nb>=8) row-major
// into Yv. BN stats (sum, sumsq per channel) fused into the epilogue.
__global__ __launch_bounds__(256)
void k_qkv_gemm(const unsigned short* __restrict__ X,
                const unsigned short* __restrict__ Wt,
                float* __restrict__ YQK, float* __restrict__ Yv,
                double* __restrict__ st){
  __shared__ __align__(16) unsigned short At[64*264];
  __shared__ __align__(16) unsigned short Bt[64*264];
  int tid = threadIdx.x;
  int mb = blockIdx.x, nb = blockIdx.y;
#pragma unroll
  for (int it = 0; it < 8; ++it){
    int s = it*256 + tid;
    int row = s >> 5, ch = s & 31;
    uint4 a = *(const uint4*)(X  + ((size_t)(mb*64 + row))*256 + ch*8);
    uint4 b = *(const uint4*)(Wt + ((size_t)(nb*64 + row))*256 + ch*8);
    *(uint4*)(At + row*264 + ch*8) = a;
    *(uint4*)(Bt + row*264 + ch*8) = b;
  }
  __syncthreads();
  int lane = tid & 63, wv = tid >> 6;
  int ln15 = lane & 15, quad = lane >> 4;
  int rw = (wv & 1)*32, cw = (wv >> 1)*32;     // 2x2 waves, 32x32 each
  f32x4 acc[2][2] = {};
#pragma unroll
  for (int ks = 0; ks < 8; ++ks){
    short8 afr[2], bfr[2];
#pragma unroll
    for (int mt = 0; mt < 2; ++mt){
      int r = rw + mt*16 + ln15;
      afr[mt] = *(const short8*)(At + r*264 + (ks*4+quad)*8);
    }
#pragma unroll
    for (int nt = 0; nt < 2; ++nt){
      int r = cw + nt*16 + ln15;
      bfr[nt] = *(const short8*)(Bt + r*264 + (ks*4+quad)*8);
    }
#pragma unroll
    for (int mt = 0; mt < 2; ++mt)
#pragma unroll
      for (int nt = 0; nt < 2; ++nt)
        acc[mt][nt] = __builtin_amdgcn_mfma_f32_16x16x32_bf16(afr[mt], bfr[nt], acc[mt][nt], 0,0,0);
  }
  // ---- per-lane column partials for BN stats (raw Y values)
  float ps[2] = {0.f, 0.f}, pq[2] = {0.f, 0.f};
#pragma unroll
  for (int mt = 0; mt < 2; ++mt)
#pragma unroll
    for (int nt = 0; nt < 2; ++nt)
#pragma unroll
      for (int r = 0; r < 4; ++r){
        float v = acc[mt][nt][r];
        ps[nt] += v; pq[nt] += v*v;
      }
  // ---- C-store
  if (nb < 8){
    int proj = nb >> 2;
    float* base = YQK + (size_t)proj*(16384*256);
    int l5c = ln15 >> 3, j = ln15 & 7;
#pragma unroll
    for (int mt = 0; mt < 2; ++mt){
      int g = (mb*64 + rw + mt*16) >> 5;
      int l31r0 = ((rw + mt*16) & 31) + quad*4;
#pragma unroll
      for (int nt = 0; nt < 2; ++nt){
        int ks2 = ((nb & 3)*64 + cw + nt*16) >> 4;
#pragma unroll
        for (int r = 0; r < 4; ++r){
          size_t chunk = (size_t)((g*16 + ks2)*64 + l5c*32 + l31r0 + r);
          base[chunk*8 + j] = acc[mt][nt][r];
        }
      }
    }
  } else {
    int vc0 = (nb - 8)*64 + cw;
#pragma unroll
    for (int mt = 0; mt < 2; ++mt)
#pragma unroll
      for (int nt = 0; nt < 2; ++nt)
#pragma unroll
        for (int r = 0; r < 4; ++r){
          int row = mb*64 + rw + mt*16 + quad*4 + r;
          Yv[(size_t)row*256 + vc0 + nt*16 + ln15] = acc[mt][nt][r];
        }
  }
  // ---- stats reduce: LDS (reuse At) then one f64 atomic pair per channel
  __syncthreads();
  float* red = (float*)At;               // [0..64) sum, [64..128) sumsq
  if (tid < 128) red[tid] = 0.f;
  __syncthreads();
#pragma unroll
  for (int nt = 0; nt < 2; ++nt){
    int colL = cw + nt*16 + ln15;        // 0..63
    atomicAdd(&red[colL],      ps[nt]);
    atomicAdd(&red[64 + colL], pq[nt]);
  }
  __syncthreads();
  if (tid < 64){
    int cc = nb*64 + tid;                // global channel 0..767
    atomicAdd(&st[cc],       (double)red[tid]);
    atomicAdd(&st[768 + cc], (double)red[64 + tid]);
  }
}

// ------------------------------------------------- BN+leaky: Q,K frag stream
// + V transpose, one dispatch. Coefs computed inline from st.
// Q coefs carry an extra 1/16 (score scale folded in; exact exponent shift).
__global__ __launch_bounds__(256)
void k_bn(const float* __restrict__ YQK, const float* __restrict__ Yv,
          const double* __restrict__ st,
          const float* __restrict__ gq, const float* __restrict__ bq,
          const float* __restrict__ gk, const float* __restrict__ bk,
          const float* __restrict__ gv, const float* __restrict__ bv,
          unsigned short* __restrict__ Qf, unsigned short* __restrict__ Kf,
          unsigned short* __restrict__ Vf){
  __shared__ float sc_s[256], sh_s[256];
  __shared__ unsigned short tile[64][66];
  int tid = threadIdx.x;
  int blk = blockIdx.x;
  if (blk < 4096){
    int proj = blk >> 11;                        // 2048 blocks per proj (0=Q,1=K)
    {
      int c = tid;
      int cc = proj*256 + c;
      double mu  = st[cc]     * (1.0/NTOT);
      double var = st[768+cc] * (1.0/NTOT) - mu*mu;
      double g = proj ? (double)gk[c] : (double)gq[c];
      double b = proj ? (double)bk[c] : (double)bq[c];
      double a = g / sqrt(var + EPS);
      float f = proj ? 1.f : 0.0625f;            // fold 1/16 into Q
      sc_s[c] = (float)a * f;
      sh_s[c] = (float)(b - mu*a) * f;
    }
    __syncthreads();
    int oc = blk*256 + tid;                      // chunk of 8 values
    int rest = oc & 524287;
    int ks = (rest >> 6) & 15, l5c = (rest >> 5) & 1;
    int ch0 = ks*16 + l5c*8;
    const float* src = YQK + (size_t)oc*8;
    float4 v0 = *(const float4*)(src);
    float4 v1 = *(const float4*)(src + 4);
    const float* sc = sc_s + ch0;
    const float* sh = sh_s + ch0;
    unsigned short r[8];
    r[0]=f2bf(lrelu(v0.x*sc[0]+sh[0])); r[1]=f2bf(lrelu(v0.y*sc[1]+sh[1]));
    r[2]=f2bf(lrelu(v0.z*sc[2]+sh[2])); r[3]=f2bf(lrelu(v0.w*sc[3]+sh[3]));
    r[4]=f2bf(lrelu(v1.x*sc[4]+sh[4])); r[5]=f2bf(lrelu(v1.y*sc[5]+sh[5]));
    r[6]=f2bf(lrelu(v1.z*sc[6]+sh[6])); r[7]=f2bf(lrelu(v1.w*sc[7]+sh[7]));
    uint4 u;
    u.x = (unsigned)r[0] | ((unsigned)r[1]<<16);
    u.y = (unsigned)r[2] | ((unsigned)r[3]<<16);
    u.z = (unsigned)r[4] | ((unsigned)r[5]<<16);
    u.w = (unsigned)r[6] | ((unsigned)r[7]<<16);
    *(uint4*)((proj ? Kf : Qf) + (size_t)rest*8) = u;
  } else {
    int b2 = blk - 4096;
    int pt = b2 & 63, ct = (b2 >> 6) & 3, b = b2 >> 8;
    if (tid < 64){
      int c = ct*64 + tid;
      int cc = 512 + c;
      double mu  = st[cc]     * (1.0/NTOT);
      double var = st[768+cc] * (1.0/NTOT) - mu*mu;
      double a = (double)gv[c] / sqrt(var + EPS);
      sc_s[tid] = (float)a;
      sh_s[tid] = (float)((double)bv[c] - mu*a);
    }
    __syncthreads();
    int cl = tid & 63, rq = tid >> 6;
    int c  = ct*64 + cl;
    float sc = sc_s[cl], sh = sh_s[cl];
#pragma unroll 4
    for (int k = 0; k < 16; ++k){
      int r = k*4 + rq;
      size_t t = (size_t)b*4096 + pt*64 + r;
      float v = Yv[t*256 + c];
      tile[r][cl] = f2bf(lrelu(v*sc + sh));
    }
    __syncthreads();
#pragma unroll
    for (int it = 0; it < 2; ++it){
      int m = it*256 + tid;                      // 512 chunks of 8 keys
      int c2 = m >> 3, kg = m & 7;
      int ch = ct*64 + c2;
      int gc = b*8 + (ch >> 5), l31c = ch & 31;
      int kp = pt*4 + (kg >> 1), l5k = kg & 1;
      unsigned short r0 = tile[kg*8+0][c2], r1 = tile[kg*8+1][c2];
      unsigned short r2 = tile[kg*8+2][c2], r3 = tile[kg*8+3][c2];
      unsigned short r4 = tile[kg*8+4][c2], r5 = tile[kg*8+5][c2];
      unsigned short r6 = tile[kg*8+6][c2], r7 = tile[kg*8+7][c2];
      uint4 u;
      u.x = (unsigned)r0 | ((unsigned)r1<<16);
      u.y = (unsigned)r2 | ((unsigned)r3<<16);
      u.z = (unsigned)r4 | ((unsigned)r5<<16);
      u.w = (unsigned)r6 | ((unsigned)r7<<16);
      *(uint4*)(Vf + ((size_t)((gc*256 + kp)*64 + l5k*32 + l31c))*8) = u;
    }
  }
}

// --------------------------------------------------------------- attention
// EXACT R2 structure (best measured 74.9us): 512 blocks x 512 threads,
// q-tile 64. blk&7 = (b,half) -> XCD-pinned. 8 iters of BK=256, 2 barriers/
// iter. setprio(1) wraps MFMA phases. No tail fusion (R12 lesson).
__global__ __launch_bounds__(512, 4)
void k_attn(const unsigned short* __restrict__ Qf,
            const unsigned short* __restrict__ Kf,
            const unsigned short* __restrict__ Vf,
            float* __restrict__ P0, float* __restrict__ P1){
  __shared__ __align__(16) unsigned short Ql[64*256];   // frag-major Q tile
  __shared__ __align__(16) unsigned short Sl[64*264];   // [q][key] padded
  int tid = threadIdx.x;
  int blk = blockIdx.x;
  int qt = blk >> 3, combo = blk & 7;
  int b = combo >> 1, half = combo & 1;
  int q0 = qt*64;
  int lane = tid & 63, w = tid >> 6;
  int l31 = lane & 31, l5 = lane >> 5;
  float* P = half ? P1 : P0;

  int gq0 = b*128 + qt*2;
  {
    const uint4* src = (const uint4*)(Qf + (size_t)gq0*8192);
    uint4* dst = (uint4*)Ql;
#pragma unroll
    for (int it = 0; it < 4; ++it) dst[it*512 + tid] = src[it*512 + tid];
  }
  __syncthreads();

  f32x16 acc2[2] = {};
  int gk0 = b*128 + half*64 + w;
  const unsigned short* kb = Kf + (size_t)gk0*8192 + lane*8;
  const unsigned short* vb = Vf + ((size_t)((b*8 + w)*256 + half*128))*512 + lane*8;
  const unsigned short* qa0 = Ql + lane*8;
  const unsigned short* qa1 = Ql + 16*512 + lane*8;

  for (int kt = 0; kt < 8; ++kt){
    f32x16 a1[2] = {};
    const unsigned short* kbt = kb + (size_t)kt*8*8192;
    __builtin_amdgcn_s_setprio(1);
#pragma unroll
    for (int ks = 0; ks < 16; ++ks){
      short8 kf = *(const short8*)(kbt + ks*512);
      short8 q0v = *(const short8*)(qa0 + ks*512);
      short8 q1v = *(const short8*)(qa1 + ks*512);
      a1[0] = __builtin_amdgcn_mfma_f32_32x32x16_bf16(q0v, kf, a1[0], 0, 0, 0);
      a1[1] = __builtin_amdgcn_mfma_f32_32x32x16_bf16(q1v, kf, a1[1], 0, 0, 0);
    }
    __builtin_amdgcn_s_setprio(0);
    __syncthreads();     // B0
#pragma unroll
    for (int reg = 0; reg < 16; ++reg){
      int rloc = (reg & 3) + 8*(reg >> 2) + 4*l5;
      float x0 = a1[0][reg], x1 = a1[1][reg];
      Sl[rloc*264 + w*32 + l31]        = f2bf(fmaxf(x0, 0.3f*x0));
      Sl[(32 + rloc)*264 + w*32 + l31] = f2bf(fmaxf(x1, 0.3f*x1));
    }
    __syncthreads();     // B1
    const unsigned short* vbt = vb + (size_t)kt*16*512;
    __builtin_amdgcn_s_setprio(1);
#pragma unroll
    for (int kk = 0; kk < 16; ++kk){
      short8 vf = *(const short8*)(vbt + kk*512);
      short8 s0 = *(const short8*)(Sl + (     l31)*264 + kk*16 + l5*8);
      short8 s1 = *(const short8*)(Sl + (32 + l31)*264 + kk*16 + l5*8);
      acc2[0] = __builtin_amdgcn_mfma_f32_32x32x16_bf16(s0, vf, acc2[0], 0, 0, 0);
      acc2[1] = __builtin_amdgcn_mfma_f32_32x32x16_bf16(s1, vf, acc2[1], 0, 0, 0);
    }
    __builtin_amdgcn_s_setprio(0);
  }
#pragma unroll
  for (int c = 0; c < 2; ++c)
#pragma unroll
    for (int reg = 0; reg < 16; ++reg){
      int row = q0 + c*32 + (reg & 3) + 8*(reg >> 2) + 4*l5;
      P[((size_t)b*4096 + row)*256 + w*32 + l31] = acc2[c][reg];
    }
}

// ---------------------------------------- fused reduce+BN-stats+softmax
// Cooperative, 512 blocks x 256 threads (all resident; LDS 0). Thread =
// channel tid, rows blk*32..+32. The 32 values live in registers across
// both grid.sync()s (fully unrolled -> static indexing, no scratch).
// phase1: v = P0+P1, BN-stat atomics. sync. phase2: coefs from st, exp,
// per-channel spatial-sum atomics. sync. phase3: scale by 1/sum, write out.
__global__ __launch_bounds__(256)
void k_rs(const float* __restrict__ P0, const float* __restrict__ P1,
          double* __restrict__ st, const float* __restrict__ g1,
          float* __restrict__ sums, float* __restrict__ out){
  int tid = threadIdx.x;
  int blk = blockIdx.x;            // 0..511
  int r0 = blk*32;
  int b = blk >> 7;                // 128 blocks per batch
  float e[32];
  double sum = 0.0, sq = 0.0;
#pragma unroll
  for (int r = 0; r < 32; ++r){
    size_t idx = (size_t)(r0 + r)*256 + tid;
    float v = P0[idx] + P1[idx];
    e[r] = v;
    sum += v; sq += (double)v*v;
  }
  atomicAdd(&st[1536 + tid], sum);
  atomicAdd(&st[1792 + tid], sq);
  cg::this_grid().sync();
  double mu  = st[1536 + tid]*(1.0/NTOT);
  double var = st[1792 + tid]*(1.0/NTOT) - mu*mu;
  double ad  = (double)g1[tid] / sqrt(var + EPS);
  float a = (float)ad, K = (float)(ad*mu);
  float s = 0.f;
#pragma unroll
  for (int r = 0; r < 32; ++r){
    e[r] = __expf(e[r]*a - K);
    s += e[r];
  }
  atomicAdd(&sums[b*256 + tid], s);
  cg::this_grid().sync();
  float rl = 1.f / sums[b*256 + tid];
#pragma unroll
  for (int r = 0; r < 32; ++r){
    size_t idx = (size_t)(r0 + r)*256 + tid;
    out[idx] = e[r]*rl;
  }
}

// ---------------------------------------------------------------------------
extern "C" void kernel_launch(void* const* d_in, const int* in_sizes, int n_in,
                              void* d_out, int out_size, void* d_ws, size_t ws_size,
                              hipStream_t stream){
  (void)in_sizes; (void)n_in; (void)out_size; (void)ws_size;
  const float* X  = (const float*)d_in[0];
  const float* Wq = (const float*)d_in[1];
  const float* gq = (const float*)d_in[2];
  const float* bq = (const float*)d_in[3];
  const float* Wk = (const float*)d_in[4];
  const float* gk = (const float*)d_in[5];
  const float* bk = (const float*)d_in[6];
  const float* Wv = (const float*)d_in[7];
  const float* gv = (const float*)d_in[8];
  const float* bv = (const float*)d_in[9];
  const float* g1 = (const float*)d_in[10];
  // d_in[11] = b1: cancels inside the spatial softmax

  char* ws = (char*)d_ws;
  double*         st   = (double*)ws;                        // 2048 f64 (16KB)
  float*          sums = (float*)(ws + 16384);               // 4KB
  unsigned short* Wt   = (unsigned short*)(ws + 26624);      // 768x256 bf16
  unsigned short* Xb   = (unsigned short*)(ws + 419840);     // 16384x256 bf16
  float*          YQK  = (float*)(ws + 8808448);             // 2x16384x256 f32 (frag-major)
  float*          Yv   = (float*)(ws + 42362880);            // 16384x256 f32 row-major
  unsigned short* Kf   = (unsigned short*)(ws + 59140096);   // frag-major 8MB
  unsigned short* Vf   = (unsigned short*)(ws + 67528704);   // frag-major 8MB
  // overlays: Qf on Xb (dead after GEMM); P0|P1 on YQK (dead after bn)
  unsigned short* Qf   = Xb;
  float*          P0   = YQK;
  float*          P1   = (float*)((char*)YQK + 16777216);
  float*          outp = (float*)d_out;

  k_prep    <<<4864, 256, 0, stream>>>(X, Wq, Wk, Wv, Xb, Wt, (float*)st);
  k_qkv_gemm<<<dim3(256,12), 256, 0, stream>>>(Xb, Wt, YQK, Yv, st);
  k_bn      <<<5120, 256, 0, stream>>>(YQK, Yv, st, gq, bq, gk, bk, gv, bv, Qf, Kf, Vf);
  k_attn    <<<512, 512, 0, stream>>>(Qf, Kf, Vf, P0, P1);
  {
    void* sargs[6];
    sargs[0] = (void*)&P0;
    sargs[1] = (void*)&P1;
    sargs[2] = (void*)&st;
    sargs[3] = (void*)&g1;
    sargs[4] = (void*)&sums;
    sargs[5] = (void*)&outp;
    hipLaunchCooperativeKernel((const void*)k_rs, dim3(512,1,1), dim3(256,1,1),
                               sargs, 0, stream);
  }
}

// Round 7
// 242.750 us; speedup vs baseline: 1.8899x; 1.4697x over previous
//
#include <hip/hip_runtime.h>
#include <stdint.h>

// ---------------------------------------------------------------------------
// GroupAttentionLayer: RF=16,STRIDE=16 windows tile the image exactly =>
//   yout = leaky(Q K^T / 16) V  (full dense attention per batch), then BN +
//   spatial softmax (mu/beta cancel; only a_c = g1/sqrt(var+eps) survives).
// B=4, P=4096 px/batch (T=16384 rows), C=256. Inputs fp32, OUTPUT fp32.
// R7:  k_attn operands FRAGMENT-MAJOR in global (lane-contiguous 1KB loads).
// R8:  BN stats fused into GEMM epilogue; frag-major fp32 YQK; setprio (+7%).
// R9:  launch fusion (7 kernels); coefs inline in k_bn; 1/16 into Q coefs.
// R10: q-tile 128 -> SLOWER (latency-bound at 1 blk/CU). REVERTED.
// R11: Gram-matrix analytic stats -> REGRESSION (+26us). REVERTED.
// R12: split-K fusion w/ __threadfence -> CATASTROPHIC (L2 flush). REVERTED.
// R13: cooperative grid.sync tail -> k_rs 105us for 50MB (device-scope sync
//      cost at low occupancy). REVERTED. Twice-confirmed: cross-XCD
//      producer/consumer inside a kernel loses to a kernel boundary.
// R14 (this round): R9 pipeline restored verbatim (best measured), plus:
//   * tail VECTORIZED: k_red/soft1/soft2 use float4 (16B/lane) with f32 LDS
//     pg-reduce before the f64 global atomics (same accumulation classes).
//   * k_qkv_gemm grid swapped to (nb,mb)=(12,256): consecutive blocks share
//     the A-tile; Xb L3 re-stream 96MB -> ~64MB; Wt L2-resident.
//   Qf/Kf[((g*16+ks)*64+lane)*8+j] : row=g*32+(lane&31), ch=ks*16+(lane>>5)*8+j
//   Vf[((gc*256+kp)*64+lane)*8+j]  : ch=(gc&7)*32+(lane&31), key=kp*16+(lane>>5)*8+j
// ---------------------------------------------------------------------------

typedef __attribute__((ext_vector_type(8)))  short short8;   // 8 x bf16
typedef __attribute__((ext_vector_type(4)))  float f32x4;    // 16x16 acc
typedef __attribute__((ext_vector_type(16))) float f32x16;   // 32x32 acc
typedef __attribute__((ext_vector_type(4)))  unsigned short ushort4v;

#define ALPHA 0.3f
#define EPS   1e-3
#define NTOT  16384.0

__device__ __forceinline__ unsigned short f2bf(float f){
  unsigned u = __float_as_uint(f);
  u += 0x7FFFu + ((u>>16)&1u);          // RNE
  return (unsigned short)(u>>16);
}
__device__ __forceinline__ float lrelu(float x){ return fmaxf(x, ALPHA*x); }

// ------------------------------------------------- prep: cvt + wtrans + zero
// blocks [0,4096): X fp32->bf16.  blocks [4096,4864): W transpose->bf16;
// zero range covers st (2048 f64 = 4096 f32) + sums (1024 f32) = 5120 f32.
__global__ __launch_bounds__(256)
void k_prep(const float* __restrict__ X,
            const float* __restrict__ Wq,
            const float* __restrict__ Wk,
            const float* __restrict__ Wv,
            unsigned short* __restrict__ Xb,
            unsigned short* __restrict__ Wt,
            float* __restrict__ zws){
  int blk = blockIdx.x, tid = threadIdx.x;
  if (blk < 4096){
    int i = (blk*256 + tid)*4;
    float4 v = *(const float4*)(X + i);
    ushort4v o; o.x = f2bf(v.x); o.y = f2bf(v.y); o.z = f2bf(v.z); o.w = f2bf(v.w);
    *(ushort4v*)(Xb + i) = o;
  } else {
    int o = (blk - 4096)*256 + tid;              // 0 .. 196607
    int p = o >> 16, rem = o & 65535;
    int j = rem >> 8, c = rem & 255;
    const float* W = (p==0) ? Wq : ((p==1) ? Wk : Wv);
    Wt[o] = f2bf(W[c*256 + j]);
    if (o < 5120) zws[o] = 0.f;                  // st + sums
  }
}

// --------------------------------------------------------------- QKV GEMM
// Y[t][n] = sum_c Xb[t][c] * Wt[n][c],  t<16384, n<768.
// Grid (nb,mb): consecutive blocks share the A-tile (L2 reuse).
// Q/K planes (nb<8) written fragment-major fp32 into YQK; V (nb>=8) row-major
// into Yv. BN stats (sum, sumsq per channel) fused into the epilogue.
__global__ __launch_bounds__(256)
void k_qkv_gemm(const unsigned short* __restrict__ X,
                const unsigned short* __restrict__ Wt,
                float* __restrict__ YQK, float* __restrict__ Yv,
                double* __restrict__ st){
  __shared__ __align__(16) unsigned short At[64*264];
  __shared__ __align__(16) unsigned short Bt[64*264];
  int tid = threadIdx.x;
  int nb = blockIdx.x, mb = blockIdx.y;
#pragma unroll
  for (int it = 0; it < 8; ++it){
    int s = it*256 + tid;
    int row = s >> 5, ch = s & 31;
    uint4 a = *(const uint4*)(X  + ((size_t)(mb*64 + row))*256 + ch*8);
    uint4 b = *(const uint4*)(Wt + ((size_t)(nb*64 + row))*256 + ch*8);
    *(uint4*)(At + row*264 + ch*8) = a;
    *(uint4*)(Bt + row*264 + ch*8) = b;
  }
  __syncthreads();
  int lane = tid & 63, wv = tid >> 6;
  int ln15 = lane & 15, quad = lane >> 4;
  int rw = (wv & 1)*32, cw = (wv >> 1)*32;     // 2x2 waves, 32x32 each
  f32x4 acc[2][2] = {};
#pragma unroll
  for (int ks = 0; ks < 8; ++ks){
    short8 afr[2], bfr[2];
#pragma unroll
    for (int mt = 0; mt < 2; ++mt){
      int r = rw + mt*16 + ln15;
      afr[mt] = *(const short8*)(At + r*264 + (ks*4+quad)*8);
    }
#pragma unroll
    for (int nt = 0; nt < 2; ++nt){
      int r = cw + nt*16 + ln15;
      bfr[nt] = *(const short8*)(Bt + r*264 + (ks*4+quad)*8);
    }
#pragma unroll
    for (int mt = 0; mt < 2; ++mt)
#pragma unroll
      for (int nt = 0; nt < 2; ++nt)
        acc[mt][nt] = __builtin_amdgcn_mfma_f32_16x16x32_bf16(afr[mt], bfr[nt], acc[mt][nt], 0,0,0);
  }
  // ---- per-lane column partials for BN stats (raw Y values)
  float ps[2] = {0.f, 0.f}, pq[2] = {0.f, 0.f};
#pragma unroll
  for (int mt = 0; mt < 2; ++mt)
#pragma unroll
    for (int nt = 0; nt < 2; ++nt)
#pragma unroll
      for (int r = 0; r < 4; ++r){
        float v = acc[mt][nt][r];
        ps[nt] += v; pq[nt] += v*v;
      }
  // ---- C-store
  if (nb < 8){
    int proj = nb >> 2;
    float* base = YQK + (size_t)proj*(16384*256);
    int l5c = ln15 >> 3, j = ln15 & 7;
#pragma unroll
    for (int mt = 0; mt < 2; ++mt){
      int g = (mb*64 + rw + mt*16) >> 5;
      int l31r0 = ((rw + mt*16) & 31) + quad*4;
#pragma unroll
      for (int nt = 0; nt < 2; ++nt){
        int ks2 = ((nb & 3)*64 + cw + nt*16) >> 4;
#pragma unroll
        for (int r = 0; r < 4; ++r){
          size_t chunk = (size_t)((g*16 + ks2)*64 + l5c*32 + l31r0 + r);
          base[chunk*8 + j] = acc[mt][nt][r];
        }
      }
    }
  } else {
    int vc0 = (nb - 8)*64 + cw;
#pragma unroll
    for (int mt = 0; mt < 2; ++mt)
#pragma unroll
      for (int nt = 0; nt < 2; ++nt)
#pragma unroll
        for (int r = 0; r < 4; ++r){
          int row = mb*64 + rw + mt*16 + quad*4 + r;
          Yv[(size_t)row*256 + vc0 + nt*16 + ln15] = acc[mt][nt][r];
        }
  }
  // ---- stats reduce: LDS (reuse At) then one f64 atomic pair per channel
  __syncthreads();
  float* red = (float*)At;               // [0..64) sum, [64..128) sumsq
  if (tid < 128) red[tid] = 0.f;
  __syncthreads();
#pragma unroll
  for (int nt = 0; nt < 2; ++nt){
    int colL = cw + nt*16 + ln15;        // 0..63
    atomicAdd(&red[colL],      ps[nt]);
    atomicAdd(&red[64 + colL], pq[nt]);
  }
  __syncthreads();
  if (tid < 64){
    int cc = nb*64 + tid;                // global channel 0..767
    atomicAdd(&st[cc],       (double)red[tid]);
    atomicAdd(&st[768 + cc], (double)red[64 + tid]);
  }
}

// ------------------------------------------------- BN+leaky: Q,K frag stream
// + V transpose, one dispatch. Coefs computed inline from st.
// Q coefs carry an extra 1/16 (score scale folded in; exact exponent shift).
__global__ __launch_bounds__(256)
void k_bn(const float* __restrict__ YQK, const float* __restrict__ Yv,
          const double* __restrict__ st,
          const float* __restrict__ gq, const float* __restrict__ bq,
          const float* __restrict__ gk, const float* __restrict__ bk,
          const float* __restrict__ gv, const float* __restrict__ bv,
          unsigned short* __restrict__ Qf, unsigned short* __restrict__ Kf,
          unsigned short* __restrict__ Vf){
  __shared__ float sc_s[256], sh_s[256];
  __shared__ unsigned short tile[64][66];
  int tid = threadIdx.x;
  int blk = blockIdx.x;
  if (blk < 4096){
    int proj = blk >> 11;                        // 2048 blocks per proj (0=Q,1=K)
    {
      int c = tid;
      int cc = proj*256 + c;
      double mu  = st[cc]     * (1.0/NTOT);
      double var = st[768+cc] * (1.0/NTOT) - mu*mu;
      double g = proj ? (double)gk[c] : (double)gq[c];
      double b = proj ? (double)bk[c] : (double)bq[c];
      double a = g / sqrt(var + EPS);
      float f = proj ? 1.f : 0.0625f;            // fold 1/16 into Q
      sc_s[c] = (float)a * f;
      sh_s[c] = (float)(b - mu*a) * f;
    }
    __syncthreads();
    int oc = blk*256 + tid;                      // chunk of 8 values
    int rest = oc & 524287;
    int ks = (rest >> 6) & 15, l5c = (rest >> 5) & 1;
    int ch0 = ks*16 + l5c*8;
    const float* src = YQK + (size_t)oc*8;
    float4 v0 = *(const float4*)(src);
    float4 v1 = *(const float4*)(src + 4);
    const float* sc = sc_s + ch0;
    const float* sh = sh_s + ch0;
    unsigned short r[8];
    r[0]=f2bf(lrelu(v0.x*sc[0]+sh[0])); r[1]=f2bf(lrelu(v0.y*sc[1]+sh[1]));
    r[2]=f2bf(lrelu(v0.z*sc[2]+sh[2])); r[3]=f2bf(lrelu(v0.w*sc[3]+sh[3]));
    r[4]=f2bf(lrelu(v1.x*sc[4]+sh[4])); r[5]=f2bf(lrelu(v1.y*sc[5]+sh[5]));
    r[6]=f2bf(lrelu(v1.z*sc[6]+sh[6])); r[7]=f2bf(lrelu(v1.w*sc[7]+sh[7]));
    uint4 u;
    u.x = (unsigned)r[0] | ((unsigned)r[1]<<16);
    u.y = (unsigned)r[2] | ((unsigned)r[3]<<16);
    u.z = (unsigned)r[4] | ((unsigned)r[5]<<16);
    u.w = (unsigned)r[6] | ((unsigned)r[7]<<16);
    *(uint4*)((proj ? Kf : Qf) + (size_t)rest*8) = u;
  } else {
    int b2 = blk - 4096;
    int pt = b2 & 63, ct = (b2 >> 6) & 3, b = b2 >> 8;
    if (tid < 64){
      int c = ct*64 + tid;
      int cc = 512 + c;
      double mu  = st[cc]     * (1.0/NTOT);
      double var = st[768+cc] * (1.0/NTOT) - mu*mu;
      double a = (double)gv[c] / sqrt(var + EPS);
      sc_s[tid] = (float)a;
      sh_s[tid] = (float)((double)bv[c] - mu*a);
    }
    __syncthreads();
    int cl = tid & 63, rq = tid >> 6;
    int c  = ct*64 + cl;
    float sc = sc_s[cl], sh = sh_s[cl];
#pragma unroll 4
    for (int k = 0; k < 16; ++k){
      int r = k*4 + rq;
      size_t t = (size_t)b*4096 + pt*64 + r;
      float v = Yv[t*256 + c];
      tile[r][cl] = f2bf(lrelu(v*sc + sh));
    }
    __syncthreads();
#pragma unroll
    for (int it = 0; it < 2; ++it){
      int m = it*256 + tid;                      // 512 chunks of 8 keys
      int c2 = m >> 3, kg = m & 7;
      int ch = ct*64 + c2;
      int gc = b*8 + (ch >> 5), l31c = ch & 31;
      int kp = pt*4 + (kg >> 1), l5k = kg & 1;
      unsigned short r0 = tile[kg*8+0][c2], r1 = tile[kg*8+1][c2];
      unsigned short r2 = tile[kg*8+2][c2], r3 = tile[kg*8+3][c2];
      unsigned short r4 = tile[kg*8+4][c2], r5 = tile[kg*8+5][c2];
      unsigned short r6 = tile[kg*8+6][c2], r7 = tile[kg*8+7][c2];
      uint4 u;
      u.x = (unsigned)r0 | ((unsigned)r1<<16);
      u.y = (unsigned)r2 | ((unsigned)r3<<16);
      u.z = (unsigned)r4 | ((unsigned)r5<<16);
      u.w = (unsigned)r6 | ((unsigned)r7<<16);
      *(uint4*)(Vf + ((size_t)((gc*256 + kp)*64 + l5k*32 + l31c))*8) = u;
    }
  }
}

// --------------------------------------------------------------- attention
// EXACT R2 structure (best measured 74.9us): 512 blocks x 512 threads,
// q-tile 64. blk&7 = (b,half) -> XCD-pinned. 8 iters of BK=256, 2 barriers/
// iter. setprio(1) wraps MFMA phases. No tail fusion (R12/R13 lessons).
__global__ __launch_bounds__(512, 4)
void k_attn(const unsigned short* __restrict__ Qf,
            const unsigned short* __restrict__ Kf,
            const unsigned short* __restrict__ Vf,
            float* __restrict__ P0, float* __restrict__ P1){
  __shared__ __align__(16) unsigned short Ql[64*256];   // frag-major Q tile
  __shared__ __align__(16) unsigned short Sl[64*264];   // [q][key] padded
  int tid = threadIdx.x;
  int blk = blockIdx.x;
  int qt = blk >> 3, combo = blk & 7;
  int b = combo >> 1, half = combo & 1;
  int q0 = qt*64;
  int lane = tid & 63, w = tid >> 6;
  int l31 = lane & 31, l5 = lane >> 5;
  float* P = half ? P1 : P0;

  int gq0 = b*128 + qt*2;
  {
    const uint4* src = (const uint4*)(Qf + (size_t)gq0*8192);
    uint4* dst = (uint4*)Ql;
#pragma unroll
    for (int it = 0; it < 4; ++it) dst[it*512 + tid] = src[it*512 + tid];
  }
  __syncthreads();

  f32x16 acc2[2] = {};
  int gk0 = b*128 + half*64 + w;
  const unsigned short* kb = Kf + (size_t)gk0*8192 + lane*8;
  const unsigned short* vb = Vf + ((size_t)((b*8 + w)*256 + half*128))*512 + lane*8;
  const unsigned short* qa0 = Ql + lane*8;
  const unsigned short* qa1 = Ql + 16*512 + lane*8;

  for (int kt = 0; kt < 8; ++kt){
    f32x16 a1[2] = {};
    const unsigned short* kbt = kb + (size_t)kt*8*8192;
    __builtin_amdgcn_s_setprio(1);
#pragma unroll
    for (int ks = 0; ks < 16; ++ks){
      short8 kf = *(const short8*)(kbt + ks*512);
      short8 q0v = *(const short8*)(qa0 + ks*512);
      short8 q1v = *(const short8*)(qa1 + ks*512);
      a1[0] = __builtin_amdgcn_mfma_f32_32x32x16_bf16(q0v, kf, a1[0], 0, 0, 0);
      a1[1] = __builtin_amdgcn_mfma_f32_32x32x16_bf16(q1v, kf, a1[1], 0, 0, 0);
    }
    __builtin_amdgcn_s_setprio(0);
    __syncthreads();     // B0
#pragma unroll
    for (int reg = 0; reg < 16; ++reg){
      int rloc = (reg & 3) + 8*(reg >> 2) + 4*l5;
      float x0 = a1[0][reg], x1 = a1[1][reg];
      Sl[rloc*264 + w*32 + l31]        = f2bf(fmaxf(x0, 0.3f*x0));
      Sl[(32 + rloc)*264 + w*32 + l31] = f2bf(fmaxf(x1, 0.3f*x1));
    }
    __syncthreads();     // B1
    const unsigned short* vbt = vb + (size_t)kt*16*512;
    __builtin_amdgcn_s_setprio(1);
#pragma unroll
    for (int kk = 0; kk < 16; ++kk){
      short8 vf = *(const short8*)(vbt + kk*512);
      short8 s0 = *(const short8*)(Sl + (     l31)*264 + kk*16 + l5*8);
      short8 s1 = *(const short8*)(Sl + (32 + l31)*264 + kk*16 + l5*8);
      acc2[0] = __builtin_amdgcn_mfma_f32_32x32x16_bf16(s0, vf, acc2[0], 0, 0, 0);
      acc2[1] = __builtin_amdgcn_mfma_f32_32x32x16_bf16(s1, vf, acc2[1], 0, 0, 0);
    }
    __builtin_amdgcn_s_setprio(0);
  }
#pragma unroll
  for (int c = 0; c < 2; ++c)
#pragma unroll
    for (int reg = 0; reg < 16; ++reg){
      int row = q0 + c*32 + (reg & 3) + 8*(reg >> 2) + 4*l5;
      P[((size_t)b*4096 + row)*256 + w*32 + l31] = acc2[c][reg];
    }
}

// ------------------------------------------------- partial reduce + BN stats
// 512 blocks x 32 rows, float4 path: thread owns 4 consecutive channels
// (16B/lane, wave covers one full 4KB row); f32 LDS pg-reduce, f64 atomics.
__global__ __launch_bounds__(256)
void k_red(const float* __restrict__ P0, const float* __restrict__ P1,
           float* __restrict__ yout, double* __restrict__ st){
  __shared__ float redS[4][256];
  __shared__ float redQ[4][256];
  int tid = threadIdx.x;
  int cg = (tid & 63)*4, pg = tid >> 6;
  int r0 = blockIdx.x*32;
  float s0=0,s1=0,s2=0,s3=0,q0=0,q1=0,q2=0,q3=0;
#pragma unroll
  for (int k = 0; k < 8; ++k){
    size_t idx = (size_t)(r0 + pg + k*4)*256 + cg;
    float4 a = *(const float4*)(P0 + idx);
    float4 b = *(const float4*)(P1 + idx);
    float4 v; v.x=a.x+b.x; v.y=a.y+b.y; v.z=a.z+b.z; v.w=a.w+b.w;
    *(float4*)(yout + idx) = v;
    s0 += v.x; q0 += v.x*v.x;
    s1 += v.y; q1 += v.y*v.y;
    s2 += v.z; q2 += v.z*v.z;
    s3 += v.w; q3 += v.w*v.w;
  }
  *(float4*)(&redS[pg][cg]) = make_float4(s0,s1,s2,s3);
  *(float4*)(&redQ[pg][cg]) = make_float4(q0,q1,q2,q3);
  __syncthreads();
  float s = redS[0][tid] + redS[1][tid] + redS[2][tid] + redS[3][tid];
  float q = redQ[0][tid] + redQ[1][tid] + redQ[2][tid] + redQ[3][tid];
  atomicAdd(&st[1536 + tid], (double)s);
  atomicAdd(&st[1792 + tid], (double)q);
}

// --------------------------------------------------------------- softmax
// BN => args are z-scores: no max pass needed; shift by a*mu. float4 path:
// thread owns 4 consecutive channels, 16 rows (stride 16).
__global__ __launch_bounds__(256)
void k_soft1(const float* __restrict__ yout, const double* __restrict__ st,
             const float* __restrict__ g1, float* __restrict__ sums){
  __shared__ float redL[16][64];
  __shared__ float sA[64], sK[64];
  int tid = threadIdx.x;
  int chunk = blockIdx.x, ct = blockIdx.y, b = blockIdx.z;
  int cg = (tid & 15)*4, pg = tid >> 4;
  if (tid < 64){
    int cc = ct*64 + tid;
    double mu  = st[1536 + cc]*(1.0/NTOT);
    double var = st[1792 + cc]*(1.0/NTOT) - mu*mu;
    double a = g1[cc] / sqrt(var + EPS);
    sA[tid] = (float)a;
    sK[tid] = (float)(a*mu);
  }
  __syncthreads();
  float a0=sA[cg], a1=sA[cg+1], a2=sA[cg+2], a3=sA[cg+3];
  float K0=sK[cg], K1=sK[cg+1], K2=sK[cg+2], K3=sK[cg+3];
  const float* base = yout + ((size_t)b*4096 + chunk*256)*256 + ct*64 + cg;
  float s0=0,s1=0,s2=0,s3=0;
#pragma unroll
  for (int k = 0; k < 16; ++k){
    float4 v = *(const float4*)(base + (size_t)(pg + k*16)*256);
    s0 += __expf(v.x*a0 - K0);
    s1 += __expf(v.y*a1 - K1);
    s2 += __expf(v.z*a2 - K2);
    s3 += __expf(v.w*a3 - K3);
  }
  *(float4*)(&redL[pg][cg]) = make_float4(s0,s1,s2,s3);
  __syncthreads();
  if (tid < 64){
    float tot = 0.f;
#pragma unroll
    for (int p = 0; p < 16; ++p) tot += redL[p][tid];
    atomicAdd(&sums[b*256 + ct*64 + tid], tot);
  }
}

__global__ __launch_bounds__(256)
void k_soft2(const float* __restrict__ yout, const double* __restrict__ st,
             const float* __restrict__ g1, const float* __restrict__ sums,
             float* __restrict__ out){
  __shared__ float sA[64], sK[64], sR[64];
  int tid = threadIdx.x;
  int chunk = blockIdx.x, ct = blockIdx.y, b = blockIdx.z;
  int cg = (tid & 15)*4, pg = tid >> 4;
  if (tid < 64){
    int cc = ct*64 + tid;
    double mu  = st[1536 + cc]*(1.0/NTOT);
    double var = st[1792 + cc]*(1.0/NTOT) - mu*mu;
    double a = g1[cc] / sqrt(var + EPS);
    sA[tid] = (float)a;
    sK[tid] = (float)(a*mu);
    sR[tid] = 1.f / sums[b*256 + cc];
  }
  __syncthreads();
  float a0=sA[cg], a1=sA[cg+1], a2=sA[cg+2], a3=sA[cg+3];
  float K0=sK[cg], K1=sK[cg+1], K2=sK[cg+2], K3=sK[cg+3];
  float r0=sR[cg], r1=sR[cg+1], r2=sR[cg+2], r3=sR[cg+3];
  const float* base = yout + ((size_t)b*4096 + chunk*256)*256 + ct*64 + cg;
  float* obase = out + ((size_t)b*4096 + chunk*256)*256 + ct*64 + cg;
#pragma unroll
  for (int k = 0; k < 16; ++k){
    size_t off = (size_t)(pg + k*16)*256;
    float4 v = *(const float4*)(base + off);
    float4 o;
    o.x = __expf(v.x*a0 - K0) * r0;
    o.y = __expf(v.y*a1 - K1) * r1;
    o.z = __expf(v.z*a2 - K2) * r2;
    o.w = __expf(v.w*a3 - K3) * r3;
    *(float4*)(obase + off) = o;
  }
}

// ---------------------------------------------------------------------------
extern "C" void kernel_launch(void* const* d_in, const int* in_sizes, int n_in,
                              void* d_out, int out_size, void* d_ws, size_t ws_size,
                              hipStream_t stream){
  (void)in_sizes; (void)n_in; (void)out_size; (void)ws_size;
  const float* X  = (const float*)d_in[0];
  const float* Wq = (const float*)d_in[1];
  const float* gq = (const float*)d_in[2];
  const float* bq = (const float*)d_in[3];
  const float* Wk = (const float*)d_in[4];
  const float* gk = (const float*)d_in[5];
  const float* bk = (const float*)d_in[6];
  const float* Wv = (const float*)d_in[7];
  const float* gv = (const float*)d_in[8];
  const float* bv = (const float*)d_in[9];
  const float* g1 = (const float*)d_in[10];
  // d_in[11] = b1: cancels inside the spatial softmax

  char* ws = (char*)d_ws;
  double*         st   = (double*)ws;                        // 2048 f64 (16KB)
  float*          sums = (float*)(ws + 16384);               // 4KB
  unsigned short* Wt   = (unsigned short*)(ws + 26624);      // 768x256 bf16
  unsigned short* Xb   = (unsigned short*)(ws + 419840);     // 16384x256 bf16
  float*          YQK  = (float*)(ws + 8808448);             // 2x16384x256 f32 (frag-major)
  float*          Yv   = (float*)(ws + 42362880);            // 16384x256 f32 row-major
  unsigned short* Kf   = (unsigned short*)(ws + 59140096);   // frag-major 8MB
  unsigned short* Vf   = (unsigned short*)(ws + 67528704);   // frag-major 8MB
  // overlays: Qf on Xb (dead after GEMM); P0|P1 on YQK (dead after bn);
  // yout on Yv (dead after bn)
  unsigned short* Qf   = Xb;
  float*          P0   = YQK;
  float*          P1   = (float*)((char*)YQK + 16777216);
  float*          yo   = Yv;

  k_prep    <<<4864, 256, 0, stream>>>(X, Wq, Wk, Wv, Xb, Wt, (float*)st);
  k_qkv_gemm<<<dim3(12,256), 256, 0, stream>>>(Xb, Wt, YQK, Yv, st);
  k_bn      <<<5120, 256, 0, stream>>>(YQK, Yv, st, gq, bq, gk, bk, gv, bv, Qf, Kf, Vf);
  k_attn    <<<512, 512, 0, stream>>>(Qf, Kf, Vf, P0, P1);
  k_red     <<<512, 256, 0, stream>>>(P0, P1, yo, st);
  k_soft1   <<<dim3(16,4,4), 256, 0, stream>>>(yo, st, g1, sums);
  k_soft2   <<<dim3(16,4,4), 256, 0, stream>>>(yo, st, g1, sums, (float*)d_out);
}

// Round 8
// 240.951 us; speedup vs baseline: 1.9040x; 1.0075x over previous
//
#include <hip/hip_runtime.h>
#include <stdint.h>

// ---------------------------------------------------------------------------
// GroupAttentionLayer: RF=16,STRIDE=16 windows tile the image exactly =>
//   yout = leaky(Q K^T / 16) V  (full dense attention per batch), then BN +
//   spatial softmax (mu/beta cancel; only a_c = g1/sqrt(var+eps) survives).
// B=4, P=4096 px/batch (T=16384 rows), C=256. Inputs fp32, OUTPUT fp32.
// R7:  k_attn operands FRAGMENT-MAJOR in global (lane-contiguous 1KB loads).
// R8:  BN stats fused into GEMM epilogue; frag-major YQK; setprio (+7%).
// R9:  launch fusion (7 kernels); coefs inline in k_bn; 1/16 into Q coefs.
// R10: q-tile 128 -> SLOWER (latency-bound at 1 blk/CU). REVERTED.
// R11: Gram-matrix analytic stats -> REGRESSION (+26us). REVERTED.
// R12: split-K fusion w/ __threadfence -> CATASTROPHIC (L2 flush). REVERTED.
// R13: cooperative grid.sync tail -> 105us for 50MB. REVERTED. Cross-XCD
//      producer/consumer inside a kernel loses to a kernel boundary.
// R14: float4 tail + gemm grid swap -> 242.7us (best).
// R15 (this round):
//   * Y stored BF16 (YQK frag-major + Yv row-major): stats remain fp32-exact
//     in the gemm epilogue; stored Y takes one extra RNE rounding (<=1 ulp of
//     the bf16 rounding Q/K/V get anyway; R11's coef perturbation left absmax
//     bit-identical => robust). Saves 24MB write + 24MB read.
//   * gemm XCD-pinned A-tile reuse: grid 3072 linear, xcd=g&7 owns mb group
//     xcd*32..+32; the 12 nb-blocks of each mb share one XCD's L2.
//   * k_bn V-path loads vectorized (uint4 = 8 bf16).
//   Qf/Kf[((g*16+ks)*64+lane)*8+j] : row=g*32+(lane&31), ch=ks*16+(lane>>5)*8+j
//   Vf[((gc*256+kp)*64+lane)*8+j]  : ch=(gc&7)*32+(lane&31), key=kp*16+(lane>>5)*8+j
// ---------------------------------------------------------------------------

typedef __attribute__((ext_vector_type(8)))  short short8;   // 8 x bf16
typedef __attribute__((ext_vector_type(4)))  float f32x4;    // 16x16 acc
typedef __attribute__((ext_vector_type(16))) float f32x16;   // 32x32 acc
typedef __attribute__((ext_vector_type(4)))  unsigned short ushort4v;

#define ALPHA 0.3f
#define EPS   1e-3
#define NTOT  16384.0

__device__ __forceinline__ unsigned short f2bf(float f){
  unsigned u = __float_as_uint(f);
  u += 0x7FFFu + ((u>>16)&1u);          // RNE
  return (unsigned short)(u>>16);
}
__device__ __forceinline__ float bf2f(unsigned short u){
  return __uint_as_float((unsigned)u << 16);
}
__device__ __forceinline__ float lrelu(float x){ return fmaxf(x, ALPHA*x); }

// ------------------------------------------------- prep: cvt + wtrans + zero
// blocks [0,4096): X fp32->bf16.  blocks [4096,4864): W transpose->bf16;
// zero range covers st (2048 f64 = 4096 f32) + sums (1024 f32) = 5120 f32.
__global__ __launch_bounds__(256)
void k_prep(const float* __restrict__ X,
            const float* __restrict__ Wq,
            const float* __restrict__ Wk,
            const float* __restrict__ Wv,
            unsigned short* __restrict__ Xb,
            unsigned short* __restrict__ Wt,
            float* __restrict__ zws){
  int blk = blockIdx.x, tid = threadIdx.x;
  if (blk < 4096){
    int i = (blk*256 + tid)*4;
    float4 v = *(const float4*)(X + i);
    ushort4v o; o.x = f2bf(v.x); o.y = f2bf(v.y); o.z = f2bf(v.z); o.w = f2bf(v.w);
    *(ushort4v*)(Xb + i) = o;
  } else {
    int o = (blk - 4096)*256 + tid;              // 0 .. 196607
    int p = o >> 16, rem = o & 65535;
    int j = rem >> 8, c = rem & 255;
    const float* W = (p==0) ? Wq : ((p==1) ? Wk : Wv);
    Wt[o] = f2bf(W[c*256 + j]);
    if (o < 5120) zws[o] = 0.f;                  // st + sums
  }
}

// --------------------------------------------------------------- QKV GEMM
// Y[t][n] = sum_c Xb[t][c] * Wt[n][c],  t<16384, n<768.  3072 linear blocks:
// xcd=g&7, r=g>>3, nb=r%12, mb=xcd*32+r/12 -> the 12 nb-blocks of one mb run
// on ONE XCD (round-robin dispatch) so the shared A-tile is L2-resident.
// Q/K planes (nb<8) -> frag-major BF16 YQK; V (nb>=8) -> row-major BF16 Yv.
// BN stats (sum, sumsq per channel, fp32 acc -> f64 atomics) in the epilogue.
__global__ __launch_bounds__(256)
void k_qkv_gemm(const unsigned short* __restrict__ X,
                const unsigned short* __restrict__ Wt,
                unsigned short* __restrict__ YQK, unsigned short* __restrict__ Yv,
                double* __restrict__ st){
  __shared__ __align__(16) unsigned short At[64*264];
  __shared__ __align__(16) unsigned short Bt[64*264];
  int tid = threadIdx.x;
  int g = blockIdx.x;
  int xcd = g & 7, r = g >> 3;
  int nb = r % 12, mb = xcd*32 + r/12;
#pragma unroll
  for (int it = 0; it < 8; ++it){
    int s = it*256 + tid;
    int row = s >> 5, ch = s & 31;
    uint4 a = *(const uint4*)(X  + ((size_t)(mb*64 + row))*256 + ch*8);
    uint4 b = *(const uint4*)(Wt + ((size_t)(nb*64 + row))*256 + ch*8);
    *(uint4*)(At + row*264 + ch*8) = a;
    *(uint4*)(Bt + row*264 + ch*8) = b;
  }
  __syncthreads();
  int lane = tid & 63, wv = tid >> 6;
  int ln15 = lane & 15, quad = lane >> 4;
  int rw = (wv & 1)*32, cw = (wv >> 1)*32;     // 2x2 waves, 32x32 each
  f32x4 acc[2][2] = {};
#pragma unroll
  for (int ks = 0; ks < 8; ++ks){
    short8 afr[2], bfr[2];
#pragma unroll
    for (int mt = 0; mt < 2; ++mt){
      int rr = rw + mt*16 + ln15;
      afr[mt] = *(const short8*)(At + rr*264 + (ks*4+quad)*8);
    }
#pragma unroll
    for (int nt = 0; nt < 2; ++nt){
      int rr = cw + nt*16 + ln15;
      bfr[nt] = *(const short8*)(Bt + rr*264 + (ks*4+quad)*8);
    }
#pragma unroll
    for (int mt = 0; mt < 2; ++mt)
#pragma unroll
      for (int nt = 0; nt < 2; ++nt)
        acc[mt][nt] = __builtin_amdgcn_mfma_f32_16x16x32_bf16(afr[mt], bfr[nt], acc[mt][nt], 0,0,0);
  }
  // ---- per-lane column partials for BN stats (raw Y values, fp32 acc)
  float ps[2] = {0.f, 0.f}, pq[2] = {0.f, 0.f};
#pragma unroll
  for (int mt = 0; mt < 2; ++mt)
#pragma unroll
    for (int nt = 0; nt < 2; ++nt)
#pragma unroll
      for (int rr = 0; rr < 4; ++rr){
        float v = acc[mt][nt][rr];
        ps[nt] += v; pq[nt] += v*v;
      }
  // ---- C-store (bf16)
  if (nb < 8){
    int proj = nb >> 2;
    unsigned short* base = YQK + (size_t)proj*(16384*256);
    int l5c = ln15 >> 3, j = ln15 & 7;
#pragma unroll
    for (int mt = 0; mt < 2; ++mt){
      int gg = (mb*64 + rw + mt*16) >> 5;
      int l31r0 = ((rw + mt*16) & 31) + quad*4;
#pragma unroll
      for (int nt = 0; nt < 2; ++nt){
        int ks2 = ((nb & 3)*64 + cw + nt*16) >> 4;
#pragma unroll
        for (int rr = 0; rr < 4; ++rr){
          size_t chunk = (size_t)((gg*16 + ks2)*64 + l5c*32 + l31r0 + rr);
          base[chunk*8 + j] = f2bf(acc[mt][nt][rr]);
        }
      }
    }
  } else {
    int vc0 = (nb - 8)*64 + cw;
#pragma unroll
    for (int mt = 0; mt < 2; ++mt)
#pragma unroll
      for (int nt = 0; nt < 2; ++nt)
#pragma unroll
        for (int rr = 0; rr < 4; ++rr){
          int row = mb*64 + rw + mt*16 + quad*4 + rr;
          Yv[(size_t)row*256 + vc0 + nt*16 + ln15] = f2bf(acc[mt][nt][rr]);
        }
  }
  // ---- stats reduce: LDS (reuse At) then one f64 atomic pair per channel
  __syncthreads();
  float* red = (float*)At;               // [0..64) sum, [64..128) sumsq
  if (tid < 128) red[tid] = 0.f;
  __syncthreads();
#pragma unroll
  for (int nt = 0; nt < 2; ++nt){
    int colL = cw + nt*16 + ln15;        // 0..63
    atomicAdd(&red[colL],      ps[nt]);
    atomicAdd(&red[64 + colL], pq[nt]);
  }
  __syncthreads();
  if (tid < 64){
    int cc = nb*64 + tid;                // global channel 0..767
    atomicAdd(&st[cc],       (double)red[tid]);
    atomicAdd(&st[768 + cc], (double)red[64 + tid]);
  }
}

// ------------------------------------------------- BN+leaky: Q,K frag stream
// + V transpose, one dispatch. Coefs computed inline from st. Y is BF16.
// Q coefs carry an extra 1/16 (score scale folded in; exact exponent shift).
__global__ __launch_bounds__(256)
void k_bn(const unsigned short* __restrict__ YQK, const unsigned short* __restrict__ Yv,
          const double* __restrict__ st,
          const float* __restrict__ gq, const float* __restrict__ bq,
          const float* __restrict__ gk, const float* __restrict__ bk,
          const float* __restrict__ gv, const float* __restrict__ bv,
          unsigned short* __restrict__ Qf, unsigned short* __restrict__ Kf,
          unsigned short* __restrict__ Vf){
  __shared__ float sc_s[256], sh_s[256];
  __shared__ unsigned short tile[64][66];
  int tid = threadIdx.x;
  int blk = blockIdx.x;
  if (blk < 4096){
    int proj = blk >> 11;                        // 2048 blocks per proj (0=Q,1=K)
    {
      int c = tid;
      int cc = proj*256 + c;
      double mu  = st[cc]     * (1.0/NTOT);
      double var = st[768+cc] * (1.0/NTOT) - mu*mu;
      double g = proj ? (double)gk[c] : (double)gq[c];
      double b = proj ? (double)bk[c] : (double)bq[c];
      double a = g / sqrt(var + EPS);
      float f = proj ? 1.f : 0.0625f;            // fold 1/16 into Q
      sc_s[c] = (float)a * f;
      sh_s[c] = (float)(b - mu*a) * f;
    }
    __syncthreads();
    int oc = blk*256 + tid;                      // chunk of 8 bf16 values
    int rest = oc & 524287;
    int ks = (rest >> 6) & 15, l5c = (rest >> 5) & 1;
    int ch0 = ks*16 + l5c*8;
    uint4 yin = *(const uint4*)(YQK + (size_t)oc*8);
    const unsigned short* yp = (const unsigned short*)&yin;
    const float* sc = sc_s + ch0;
    const float* sh = sh_s + ch0;
    unsigned short rr[8];
#pragma unroll
    for (int e = 0; e < 8; ++e){
      float v = bf2f(yp[e]);
      rr[e] = f2bf(lrelu(v*sc[e] + sh[e]));
    }
    uint4 u;
    u.x = (unsigned)rr[0] | ((unsigned)rr[1]<<16);
    u.y = (unsigned)rr[2] | ((unsigned)rr[3]<<16);
    u.z = (unsigned)rr[4] | ((unsigned)rr[5]<<16);
    u.w = (unsigned)rr[6] | ((unsigned)rr[7]<<16);
    *(uint4*)((proj ? Kf : Qf) + (size_t)rest*8) = u;
  } else {
    int b2 = blk - 4096;
    int pt = b2 & 63, ct = (b2 >> 6) & 3, b = b2 >> 8;
    if (tid < 64){
      int c = ct*64 + tid;
      int cc = 512 + c;
      double mu  = st[cc]     * (1.0/NTOT);
      double var = st[768+cc] * (1.0/NTOT) - mu*mu;
      double a = (double)gv[c] / sqrt(var + EPS);
      sc_s[tid] = (float)a;
      sh_s[tid] = (float)((double)bv[c] - mu*a);
    }
    __syncthreads();
    // stage 1: vectorized 8-bf16 loads, affine, LDS tile
#pragma unroll
    for (int kpass = 0; kpass < 2; ++kpass){
      int idx = kpass*256 + tid;                 // 0..511
      int px = idx >> 3, co = idx & 7;
      size_t t = (size_t)b*4096 + pt*64 + px;
      uint4 u = *(const uint4*)(Yv + t*256 + ct*64 + co*8);
      const unsigned short* up = (const unsigned short*)&u;
      int c0 = co*8;
#pragma unroll
      for (int e = 0; e < 8; ++e){
        float v = bf2f(up[e]);
        tile[px][c0+e] = f2bf(lrelu(v*sc_s[c0+e] + sh_s[c0+e]));
      }
    }
    __syncthreads();
#pragma unroll
    for (int it = 0; it < 2; ++it){
      int m = it*256 + tid;                      // 512 chunks of 8 keys
      int c2 = m >> 3, kg = m & 7;
      int ch = ct*64 + c2;
      int gc = b*8 + (ch >> 5), l31c = ch & 31;
      int kp = pt*4 + (kg >> 1), l5k = kg & 1;
      unsigned short r0 = tile[kg*8+0][c2], r1 = tile[kg*8+1][c2];
      unsigned short r2 = tile[kg*8+2][c2], r3 = tile[kg*8+3][c2];
      unsigned short r4 = tile[kg*8+4][c2], r5 = tile[kg*8+5][c2];
      unsigned short r6 = tile[kg*8+6][c2], r7 = tile[kg*8+7][c2];
      uint4 u;
      u.x = (unsigned)r0 | ((unsigned)r1<<16);
      u.y = (unsigned)r2 | ((unsigned)r3<<16);
      u.z = (unsigned)r4 | ((unsigned)r5<<16);
      u.w = (unsigned)r6 | ((unsigned)r7<<16);
      *(uint4*)(Vf + ((size_t)((gc*256 + kp)*64 + l5k*32 + l31c))*8) = u;
    }
  }
}

// --------------------------------------------------------------- attention
// EXACT R2 structure (best measured 74.9us): 512 blocks x 512 threads,
// q-tile 64. blk&7 = (b,half) -> XCD-pinned. 8 iters of BK=256, 2 barriers/
// iter. setprio(1) wraps MFMA phases. No tail fusion (R12/R13 lessons).
__global__ __launch_bounds__(512, 4)
void k_attn(const unsigned short* __restrict__ Qf,
            const unsigned short* __restrict__ Kf,
            const unsigned short* __restrict__ Vf,
            float* __restrict__ P0, float* __restrict__ P1){
  __shared__ __align__(16) unsigned short Ql[64*256];   // frag-major Q tile
  __shared__ __align__(16) unsigned short Sl[64*264];   // [q][key] padded
  int tid = threadIdx.x;
  int blk = blockIdx.x;
  int qt = blk >> 3, combo = blk & 7;
  int b = combo >> 1, half = combo & 1;
  int q0 = qt*64;
  int lane = tid & 63, w = tid >> 6;
  int l31 = lane & 31, l5 = lane >> 5;
  float* P = half ? P1 : P0;

  int gq0 = b*128 + qt*2;
  {
    const uint4* src = (const uint4*)(Qf + (size_t)gq0*8192);
    uint4* dst = (uint4*)Ql;
#pragma unroll
    for (int it = 0; it < 4; ++it) dst[it*512 + tid] = src[it*512 + tid];
  }
  __syncthreads();

  f32x16 acc2[2] = {};
  int gk0 = b*128 + half*64 + w;
  const unsigned short* kb = Kf + (size_t)gk0*8192 + lane*8;
  const unsigned short* vb = Vf + ((size_t)((b*8 + w)*256 + half*128))*512 + lane*8;
  const unsigned short* qa0 = Ql + lane*8;
  const unsigned short* qa1 = Ql + 16*512 + lane*8;

  for (int kt = 0; kt < 8; ++kt){
    f32x16 a1[2] = {};
    const unsigned short* kbt = kb + (size_t)kt*8*8192;
    __builtin_amdgcn_s_setprio(1);
#pragma unroll
    for (int ks = 0; ks < 16; ++ks){
      short8 kf = *(const short8*)(kbt + ks*512);
      short8 q0v = *(const short8*)(qa0 + ks*512);
      short8 q1v = *(const short8*)(qa1 + ks*512);
      a1[0] = __builtin_amdgcn_mfma_f32_32x32x16_bf16(q0v, kf, a1[0], 0, 0, 0);
      a1[1] = __builtin_amdgcn_mfma_f32_32x32x16_bf16(q1v, kf, a1[1], 0, 0, 0);
    }
    __builtin_amdgcn_s_setprio(0);
    __syncthreads();     // B0
#pragma unroll
    for (int reg = 0; reg < 16; ++reg){
      int rloc = (reg & 3) + 8*(reg >> 2) + 4*l5;
      float x0 = a1[0][reg], x1 = a1[1][reg];
      Sl[rloc*264 + w*32 + l31]        = f2bf(fmaxf(x0, 0.3f*x0));
      Sl[(32 + rloc)*264 + w*32 + l31] = f2bf(fmaxf(x1, 0.3f*x1));
    }
    __syncthreads();     // B1
    const unsigned short* vbt = vb + (size_t)kt*16*512;
    __builtin_amdgcn_s_setprio(1);
#pragma unroll
    for (int kk = 0; kk < 16; ++kk){
      short8 vf = *(const short8*)(vbt + kk*512);
      short8 s0 = *(const short8*)(Sl + (     l31)*264 + kk*16 + l5*8);
      short8 s1 = *(const short8*)(Sl + (32 + l31)*264 + kk*16 + l5*8);
      acc2[0] = __builtin_amdgcn_mfma_f32_32x32x16_bf16(s0, vf, acc2[0], 0, 0, 0);
      acc2[1] = __builtin_amdgcn_mfma_f32_32x32x16_bf16(s1, vf, acc2[1], 0, 0, 0);
    }
    __builtin_amdgcn_s_setprio(0);
  }
#pragma unroll
  for (int c = 0; c < 2; ++c)
#pragma unroll
    for (int reg = 0; reg < 16; ++reg){
      int row = q0 + c*32 + (reg & 3) + 8*(reg >> 2) + 4*l5;
      P[((size_t)b*4096 + row)*256 + w*32 + l31] = acc2[c][reg];
    }
}

// ------------------------------------------------- partial reduce + BN stats
// 512 blocks x 32 rows, float4 path: thread owns 4 consecutive channels
// (16B/lane, wave covers one full 4KB row); f32 LDS pg-reduce, f64 atomics.
__global__ __launch_bounds__(256)
void k_red(const float* __restrict__ P0, const float* __restrict__ P1,
           float* __restrict__ yout, double* __restrict__ st){
  __shared__ float redS[4][256];
  __shared__ float redQ[4][256];
  int tid = threadIdx.x;
  int cg = (tid & 63)*4, pg = tid >> 6;
  int r0 = blockIdx.x*32;
  float s0=0,s1=0,s2=0,s3=0,q0=0,q1=0,q2=0,q3=0;
#pragma unroll
  for (int k = 0; k < 8; ++k){
    size_t idx = (size_t)(r0 + pg + k*4)*256 + cg;
    float4 a = *(const float4*)(P0 + idx);
    float4 b = *(const float4*)(P1 + idx);
    float4 v; v.x=a.x+b.x; v.y=a.y+b.y; v.z=a.z+b.z; v.w=a.w+b.w;
    *(float4*)(yout + idx) = v;
    s0 += v.x; q0 += v.x*v.x;
    s1 += v.y; q1 += v.y*v.y;
    s2 += v.z; q2 += v.z*v.z;
    s3 += v.w; q3 += v.w*v.w;
  }
  *(float4*)(&redS[pg][cg]) = make_float4(s0,s1,s2,s3);
  *(float4*)(&redQ[pg][cg]) = make_float4(q0,q1,q2,q3);
  __syncthreads();
  float s = redS[0][tid] + redS[1][tid] + redS[2][tid] + redS[3][tid];
  float q = redQ[0][tid] + redQ[1][tid] + redQ[2][tid] + redQ[3][tid];
  atomicAdd(&st[1536 + tid], (double)s);
  atomicAdd(&st[1792 + tid], (double)q);
}

// --------------------------------------------------------------- softmax
// BN => args are z-scores: no max pass needed; shift by a*mu. float4 path.
__global__ __launch_bounds__(256)
void k_soft1(const float* __restrict__ yout, const double* __restrict__ st,
             const float* __restrict__ g1, float* __restrict__ sums){
  __shared__ float redL[16][64];
  __shared__ float sA[64], sK[64];
  int tid = threadIdx.x;
  int chunk = blockIdx.x, ct = blockIdx.y, b = blockIdx.z;
  int cg = (tid & 15)*4, pg = tid >> 4;
  if (tid < 64){
    int cc = ct*64 + tid;
    double mu  = st[1536 + cc]*(1.0/NTOT);
    double var = st[1792 + cc]*(1.0/NTOT) - mu*mu;
    double a = g1[cc] / sqrt(var + EPS);
    sA[tid] = (float)a;
    sK[tid] = (float)(a*mu);
  }
  __syncthreads();
  float a0=sA[cg], a1=sA[cg+1], a2=sA[cg+2], a3=sA[cg+3];
  float K0=sK[cg], K1=sK[cg+1], K2=sK[cg+2], K3=sK[cg+3];
  const float* base = yout + ((size_t)b*4096 + chunk*256)*256 + ct*64 + cg;
  float s0=0,s1=0,s2=0,s3=0;
#pragma unroll
  for (int k = 0; k < 16; ++k){
    float4 v = *(const float4*)(base + (size_t)(pg + k*16)*256);
    s0 += __expf(v.x*a0 - K0);
    s1 += __expf(v.y*a1 - K1);
    s2 += __expf(v.z*a2 - K2);
    s3 += __expf(v.w*a3 - K3);
  }
  *(float4*)(&redL[pg][cg]) = make_float4(s0,s1,s2,s3);
  __syncthreads();
  if (tid < 64){
    float tot = 0.f;
#pragma unroll
    for (int p = 0; p < 16; ++p) tot += redL[p][tid];
    atomicAdd(&sums[b*256 + ct*64 + tid], tot);
  }
}

__global__ __launch_bounds__(256)
void k_soft2(const float* __restrict__ yout, const double* __restrict__ st,
             const float* __restrict__ g1, const float* __restrict__ sums,
             float* __restrict__ out){
  __shared__ float sA[64], sK[64], sR[64];
  int tid = threadIdx.x;
  int chunk = blockIdx.x, ct = blockIdx.y, b = blockIdx.z;
  int cg = (tid & 15)*4, pg = tid >> 4;
  if (tid < 64){
    int cc = ct*64 + tid;
    double mu  = st[1536 + cc]*(1.0/NTOT);
    double var = st[1792 + cc]*(1.0/NTOT) - mu*mu;
    double a = g1[cc] / sqrt(var + EPS);
    sA[tid] = (float)a;
    sK[tid] = (float)(a*mu);
    sR[tid] = 1.f / sums[b*256 + cc];
  }
  __syncthreads();
  float a0=sA[cg], a1=sA[cg+1], a2=sA[cg+2], a3=sA[cg+3];
  float K0=sK[cg], K1=sK[cg+1], K2=sK[cg+2], K3=sK[cg+3];
  float r0=sR[cg], r1=sR[cg+1], r2=sR[cg+2], r3=sR[cg+3];
  const float* base = yout + ((size_t)b*4096 + chunk*256)*256 + ct*64 + cg;
  float* obase = out + ((size_t)b*4096 + chunk*256)*256 + ct*64 + cg;
#pragma unroll
  for (int k = 0; k < 16; ++k){
    size_t off = (size_t)(pg + k*16)*256;
    float4 v = *(const float4*)(base + off);
    float4 o;
    o.x = __expf(v.x*a0 - K0) * r0;
    o.y = __expf(v.y*a1 - K1) * r1;
    o.z = __expf(v.z*a2 - K2) * r2;
    o.w = __expf(v.w*a3 - K3) * r3;
    *(float4*)(obase + off) = o;
  }
}

// ---------------------------------------------------------------------------
extern "C" void kernel_launch(void* const* d_in, const int* in_sizes, int n_in,
                              void* d_out, int out_size, void* d_ws, size_t ws_size,
                              hipStream_t stream){
  (void)in_sizes; (void)n_in; (void)out_size; (void)ws_size;
  const float* X  = (const float*)d_in[0];
  const float* Wq = (const float*)d_in[1];
  const float* gq = (const float*)d_in[2];
  const float* bq = (const float*)d_in[3];
  const float* Wk = (const float*)d_in[4];
  const float* gk = (const float*)d_in[5];
  const float* bk = (const float*)d_in[6];
  const float* Wv = (const float*)d_in[7];
  const float* gv = (const float*)d_in[8];
  const float* bv = (const float*)d_in[9];
  const float* g1 = (const float*)d_in[10];
  // d_in[11] = b1: cancels inside the spatial softmax

  char* ws = (char*)d_ws;
  double*         st   = (double*)ws;                        // 2048 f64 (16KB)
  float*          sums = (float*)(ws + 16384);               // 4KB
  unsigned short* Wt   = (unsigned short*)(ws + 26624);      // 768x256 bf16 -> ends 419840
  unsigned short* Xb   = (unsigned short*)(ws + 419840);     // 8MB -> ends 8808448
  unsigned short* YQK  = (unsigned short*)(ws + 8808448);    // 16MB bf16 frag-major -> 25585664
  unsigned short* Yv   = (unsigned short*)(ws + 25585664);   // 8MB bf16 row-major -> 33974272
  unsigned short* Kf   = (unsigned short*)(ws + 33974272);   // 8MB frag-major -> 42362880
  unsigned short* Vf   = (unsigned short*)(ws + 42362880);   // 8MB frag-major -> 50751488
  float*          P1   = (float*)(ws + 50751488);            // 16MB -> 67528704
  // overlays: Qf on Xb (dead after GEMM); P0 on YQK (dead after bn);
  // yout on Kf+Vf (dead after attn)
  unsigned short* Qf   = Xb;
  float*          P0   = (float*)(ws + 8808448);
  float*          yo   = (float*)(ws + 33974272);

  k_prep    <<<4864, 256, 0, stream>>>(X, Wq, Wk, Wv, Xb, Wt, (float*)st);
  k_qkv_gemm<<<3072, 256, 0, stream>>>(Xb, Wt, YQK, Yv, st);
  k_bn      <<<5120, 256, 0, stream>>>(YQK, Yv, st, gq, bq, gk, bk, gv, bv, Qf, Kf, Vf);
  k_attn    <<<512, 512, 0, stream>>>(Qf, Kf, Vf, P0, P1);
  k_red     <<<512, 256, 0, stream>>>(P0, P1, yo, st);
  k_soft1   <<<dim3(16,4,4), 256, 0, stream>>>(yo, st, g1, sums);
  k_soft2   <<<dim3(16,4,4), 256, 0, stream>>>(yo, st, g1, sums, (float*)d_out);
}

// Round 9
// 230.007 us; speedup vs baseline: 1.9946x; 1.0476x over previous
//
#include <hip/hip_runtime.h>
#include <stdint.h>

// ---------------------------------------------------------------------------
// GroupAttentionLayer: RF=16,STRIDE=16 windows tile the image exactly =>
//   yout = leaky(Q K^T / 16) V  (full dense attention per batch), then BN +
//   spatial softmax (mu/beta cancel; only a_c = g1/sqrt(var+eps) survives).
// B=4, P=4096 px/batch (T=16384 rows), C=256. Inputs fp32, OUTPUT fp32.
// R7:  k_attn operands FRAGMENT-MAJOR in global (lane-contiguous 1KB loads).
// R8:  BN stats fused into GEMM epilogue; frag-major YQK; setprio (+7%).
// R9:  launch fusion (7 kernels); coefs inline in k_bn; 1/16 into Q coefs.
// R10: q-tile 128 -> SLOWER (latency-bound at 1 blk/CU). REVERTED.
// R11: Gram-matrix analytic stats -> REGRESSION (+26us). REVERTED.
// R12: split-K fusion w/ __threadfence -> CATASTROPHIC (L2 flush). REVERTED.
// R13: cooperative grid.sync tail -> 105us for 50MB. REVERTED.
// R14: float4 tail + gemm grid swap -> 242.7us.
// R15: bf16 Y + XCD-pinned gemm + vectorized k_bn V -> 240.95us (best),
//      absmax improved to 1.22e-4.
// R16 (this round): k_qkv_gemm rewritten to the m97 structure (the best-
//      validated GEMM template on this chip: 128x128 tile, BK=64,
//      global_load_lds width-16 staging, 2-barrier K-loop; 874-912 TF vs
//      ~343 TF for the old 64x64 reg-staged tile). 768 blocks x 256 thr.
//      Epilogue (frag-major bf16 stores + fp32->f64 BN stats) carried over
//      term-for-term. Everything else frozen at R15.
//   Qf/Kf[((g*16+ks)*64+lane)*8+j] : row=g*32+(lane&31), ch=ks*16+(lane>>5)*8+j
//   Vf[((gc*256+kp)*64+lane)*8+j]  : ch=(gc&7)*32+(lane&31), key=kp*16+(lane>>5)*8+j
// ---------------------------------------------------------------------------

typedef __attribute__((ext_vector_type(8)))  short short8;   // 8 x bf16
typedef __attribute__((ext_vector_type(4)))  float f32x4;    // 16x16 acc
typedef __attribute__((ext_vector_type(16))) float f32x16;   // 32x32 acc
typedef __attribute__((ext_vector_type(4)))  unsigned short ushort4v;

#define ALPHA 0.3f
#define EPS   1e-3
#define NTOT  16384.0

#define GLOAD_LDS16(gp, lp) __builtin_amdgcn_global_load_lds( \
    (const __attribute__((address_space(1))) void*)(gp), \
    (__attribute__((address_space(3))) void*)(lp), 16, 0, 0)

__device__ __forceinline__ unsigned short f2bf(float f){
  unsigned u = __float_as_uint(f);
  u += 0x7FFFu + ((u>>16)&1u);          // RNE
  return (unsigned short)(u>>16);
}
__device__ __forceinline__ float bf2f(unsigned short u){
  return __uint_as_float((unsigned)u << 16);
}
__device__ __forceinline__ float lrelu(float x){ return fmaxf(x, ALPHA*x); }

// ------------------------------------------------- prep: cvt + wtrans + zero
__global__ __launch_bounds__(256)
void k_prep(const float* __restrict__ X,
            const float* __restrict__ Wq,
            const float* __restrict__ Wk,
            const float* __restrict__ Wv,
            unsigned short* __restrict__ Xb,
            unsigned short* __restrict__ Wt,
            float* __restrict__ zws){
  int blk = blockIdx.x, tid = threadIdx.x;
  if (blk < 4096){
    int i = (blk*256 + tid)*4;
    float4 v = *(const float4*)(X + i);
    ushort4v o; o.x = f2bf(v.x); o.y = f2bf(v.y); o.z = f2bf(v.z); o.w = f2bf(v.w);
    *(ushort4v*)(Xb + i) = o;
  } else {
    int o = (blk - 4096)*256 + tid;              // 0 .. 196607
    int p = o >> 16, rem = o & 65535;
    int j = rem >> 8, c = rem & 255;
    const float* W = (p==0) ? Wq : ((p==1) ? Wk : Wv);
    Wt[o] = f2bf(W[c*256 + j]);
    if (o < 5120) zws[o] = 0.f;                  // st + sums
  }
}

// --------------------------------------------------------------- QKV GEMM
// m97 structure: Y[t][n] = sum_c Xb[t][c]*Wt[n][c]. 128x128 tile, BK=64,
// 768 blocks (xcd-pinned: 6 nb-blocks sharing an A-tile on one XCD), 4 waves
// (2x2, 64x64 each). A/B staged via global_load_lds dwordx4 into linear
// [128][64] LDS (lane L of segment s -> byte s*1024+L*16 = [s*8+L/8][(L&7)*8]).
// Q/K planes (nb<4) -> frag-major BF16 YQK; V (nb>=4) -> row-major BF16 Yv.
// BN stats (fp32 partials -> LDS -> f64 atomics) in the epilogue.
__global__ __launch_bounds__(256)
void k_qkv_gemm(const unsigned short* __restrict__ X,
                const unsigned short* __restrict__ Wt,
                unsigned short* __restrict__ YQK, unsigned short* __restrict__ Yv,
                double* __restrict__ st){
  __shared__ __align__(16) unsigned short At[128*64];   // 16KB
  __shared__ __align__(16) unsigned short Bt[128*64];   // 16KB
  int tid = threadIdx.x;
  int g = blockIdx.x;
  int xcd = g & 7, r8 = g >> 3;          // 96 per XCD = 16 mb x 6 nb
  int mb = xcd*16 + r8/6, nb = r8 % 6;
  int lane = tid & 63, w = tid >> 6;
  int ln15 = lane & 15, quad = lane >> 4;
  int rw = (w & 1)*64, cw = (w >> 1)*64;       // 2x2 waves, 64x64 each

  // per-lane global bases for staging (row = s*8 + lane/8, col8 = lane&7)
  const unsigned short* gaL = X  + ((size_t)(mb*128 + (lane>>3)))*256 + (lane&7)*8;
  const unsigned short* gbL = Wt + ((size_t)(nb*128 + (lane>>3)))*256 + (lane&7)*8;

  f32x4 acc[4][4] = {};
  for (int kt = 0; kt < 4; ++kt){
    const unsigned short* ga = gaL + kt*64;
    const unsigned short* gb = gbL + kt*64;
#pragma unroll
    for (int j = 0; j < 4; ++j){
      int s = w*4 + j;                         // segment 0..15
      GLOAD_LDS16(ga + (size_t)s*8*256, At + s*512);
      GLOAD_LDS16(gb + (size_t)s*8*256, Bt + s*512);
    }
    __syncthreads();                           // vmcnt(0) drained by compiler
#pragma unroll
    for (int ksub = 0; ksub < 2; ++ksub){
      short8 af[4], bf[4];
#pragma unroll
      for (int mt = 0; mt < 4; ++mt)
        af[mt] = *(const short8*)(At + (rw + mt*16 + ln15)*64 + ksub*32 + quad*8);
#pragma unroll
      for (int nt = 0; nt < 4; ++nt)
        bf[nt] = *(const short8*)(Bt + (cw + nt*16 + ln15)*64 + ksub*32 + quad*8);
#pragma unroll
      for (int mt = 0; mt < 4; ++mt)
#pragma unroll
        for (int nt = 0; nt < 4; ++nt)
          acc[mt][nt] = __builtin_amdgcn_mfma_f32_16x16x32_bf16(af[mt], bf[nt], acc[mt][nt], 0,0,0);
    }
    __syncthreads();
  }
  // ---- per-lane column partials for BN stats (raw fp32 Y values)
  float ps[4] = {0,0,0,0}, pq[4] = {0,0,0,0};
#pragma unroll
  for (int mt = 0; mt < 4; ++mt)
#pragma unroll
    for (int nt = 0; nt < 4; ++nt)
#pragma unroll
      for (int rr = 0; rr < 4; ++rr){
        float v = acc[mt][nt][rr];
        ps[nt] += v; pq[nt] += v*v;
      }
  // ---- C-store (bf16)
  if (nb < 4){
    int proj = nb >> 1;                        // 0=Q (nb 0,1), 1=K (nb 2,3)
    unsigned short* base = YQK + (size_t)proj*(16384*256);
#pragma unroll
    for (int nt = 0; nt < 4; ++nt){
      int ch_g = (nb&1)*128 + cw + nt*16 + ln15;
      int ksf = ch_g >> 4, l5c = (ch_g >> 3) & 1, j = ch_g & 7;
#pragma unroll
      for (int mt = 0; mt < 4; ++mt){
        int row0 = mb*128 + rw + mt*16 + quad*4;
        int gg = row0 >> 5, l31r0 = row0 & 31;
#pragma unroll
        for (int rr = 0; rr < 4; ++rr){
          size_t chunk = (size_t)((gg*16 + ksf)*64 + l5c*32 + l31r0 + rr);
          base[chunk*8 + j] = f2bf(acc[mt][nt][rr]);
        }
      }
    }
  } else {
    int vc0 = (nb - 4)*128 + cw;
#pragma unroll
    for (int mt = 0; mt < 4; ++mt)
#pragma unroll
      for (int nt = 0; nt < 4; ++nt)
#pragma unroll
        for (int rr = 0; rr < 4; ++rr){
          int row = mb*128 + rw + mt*16 + quad*4 + rr;
          Yv[(size_t)row*256 + vc0 + nt*16 + ln15] = f2bf(acc[mt][nt][rr]);
        }
  }
  // ---- stats reduce: LDS (reuse At, 256 f32) then f64 atomics per channel
  __syncthreads();
  float* red = (float*)At;                     // [0..128) sum, [128..256) sq
  red[tid] = 0.f;                              // 256 threads cover 256 slots
  __syncthreads();
#pragma unroll
  for (int nt = 0; nt < 4; ++nt){
    int colL = cw + nt*16 + ln15;              // 0..127
    atomicAdd(&red[colL],       ps[nt]);
    atomicAdd(&red[128 + colL], pq[nt]);
  }
  __syncthreads();
  if (tid < 128){
    int cc = nb*128 + tid;                     // global channel 0..767
    atomicAdd(&st[cc],       (double)red[tid]);
    atomicAdd(&st[768 + cc], (double)red[128 + tid]);
  }
}

// ------------------------------------------------- BN+leaky: Q,K frag stream
// + V transpose, one dispatch. Coefs computed inline from st. Y is BF16.
// Q coefs carry an extra 1/16 (score scale folded in; exact exponent shift).
__global__ __launch_bounds__(256)
void k_bn(const unsigned short* __restrict__ YQK, const unsigned short* __restrict__ Yv,
          const double* __restrict__ st,
          const float* __restrict__ gq, const float* __restrict__ bq,
          const float* __restrict__ gk, const float* __restrict__ bk,
          const float* __restrict__ gv, const float* __restrict__ bv,
          unsigned short* __restrict__ Qf, unsigned short* __restrict__ Kf,
          unsigned short* __restrict__ Vf){
  __shared__ float sc_s[256], sh_s[256];
  __shared__ unsigned short tile[64][66];
  int tid = threadIdx.x;
  int blk = blockIdx.x;
  if (blk < 4096){
    int proj = blk >> 11;                        // 2048 blocks per proj (0=Q,1=K)
    {
      int c = tid;
      int cc = proj*256 + c;
      double mu  = st[cc]     * (1.0/NTOT);
      double var = st[768+cc] * (1.0/NTOT) - mu*mu;
      double g = proj ? (double)gk[c] : (double)gq[c];
      double b = proj ? (double)bk[c] : (double)bq[c];
      double a = g / sqrt(var + EPS);
      float f = proj ? 1.f : 0.0625f;            // fold 1/16 into Q
      sc_s[c] = (float)a * f;
      sh_s[c] = (float)(b - mu*a) * f;
    }
    __syncthreads();
    int oc = blk*256 + tid;                      // chunk of 8 bf16 values
    int rest = oc & 524287;
    int ks = (rest >> 6) & 15, l5c = (rest >> 5) & 1;
    int ch0 = ks*16 + l5c*8;
    uint4 yin = *(const uint4*)(YQK + (size_t)oc*8);
    const unsigned short* yp = (const unsigned short*)&yin;
    const float* sc = sc_s + ch0;
    const float* sh = sh_s + ch0;
    unsigned short rr[8];
#pragma unroll
    for (int e = 0; e < 8; ++e){
      float v = bf2f(yp[e]);
      rr[e] = f2bf(lrelu(v*sc[e] + sh[e]));
    }
    uint4 u;
    u.x = (unsigned)rr[0] | ((unsigned)rr[1]<<16);
    u.y = (unsigned)rr[2] | ((unsigned)rr[3]<<16);
    u.z = (unsigned)rr[4] | ((unsigned)rr[5]<<16);
    u.w = (unsigned)rr[6] | ((unsigned)rr[7]<<16);
    *(uint4*)((proj ? Kf : Qf) + (size_t)rest*8) = u;
  } else {
    int b2 = blk - 4096;
    int pt = b2 & 63, ct = (b2 >> 6) & 3, b = b2 >> 8;
    if (tid < 64){
      int c = ct*64 + tid;
      int cc = 512 + c;
      double mu  = st[cc]     * (1.0/NTOT);
      double var = st[768+cc] * (1.0/NTOT) - mu*mu;
      double a = (double)gv[c] / sqrt(var + EPS);
      sc_s[tid] = (float)a;
      sh_s[tid] = (float)((double)bv[c] - mu*a);
    }
    __syncthreads();
    // stage 1: vectorized 8-bf16 loads, affine, LDS tile
#pragma unroll
    for (int kpass = 0; kpass < 2; ++kpass){
      int idx = kpass*256 + tid;                 // 0..511
      int px = idx >> 3, co = idx & 7;
      size_t t = (size_t)b*4096 + pt*64 + px;
      uint4 u = *(const uint4*)(Yv + t*256 + ct*64 + co*8);
      const unsigned short* up = (const unsigned short*)&u;
      int c0 = co*8;
#pragma unroll
      for (int e = 0; e < 8; ++e){
        float v = bf2f(up[e]);
        tile[px][c0+e] = f2bf(lrelu(v*sc_s[c0+e] + sh_s[c0+e]));
      }
    }
    __syncthreads();
#pragma unroll
    for (int it = 0; it < 2; ++it){
      int m = it*256 + tid;                      // 512 chunks of 8 keys
      int c2 = m >> 3, kg = m & 7;
      int ch = ct*64 + c2;
      int gc = b*8 + (ch >> 5), l31c = ch & 31;
      int kp = pt*4 + (kg >> 1), l5k = kg & 1;
      unsigned short r0 = tile[kg*8+0][c2], r1 = tile[kg*8+1][c2];
      unsigned short r2 = tile[kg*8+2][c2], r3 = tile[kg*8+3][c2];
      unsigned short r4 = tile[kg*8+4][c2], r5 = tile[kg*8+5][c2];
      unsigned short r6 = tile[kg*8+6][c2], r7 = tile[kg*8+7][c2];
      uint4 u;
      u.x = (unsigned)r0 | ((unsigned)r1<<16);
      u.y = (unsigned)r2 | ((unsigned)r3<<16);
      u.z = (unsigned)r4 | ((unsigned)r5<<16);
      u.w = (unsigned)r6 | ((unsigned)r7<<16);
      *(uint4*)(Vf + ((size_t)((gc*256 + kp)*64 + l5k*32 + l31c))*8) = u;
    }
  }
}

// --------------------------------------------------------------- attention
// EXACT R2 structure (best measured): 512 blocks x 512 threads, q-tile 64.
// blk&7 = (b,half) -> XCD-pinned. 8 iters of BK=256, 2 barriers/iter.
// setprio(1) wraps MFMA phases. No tail fusion (R12/R13 lessons).
__global__ __launch_bounds__(512, 4)
void k_attn(const unsigned short* __restrict__ Qf,
            const unsigned short* __restrict__ Kf,
            const unsigned short* __restrict__ Vf,
            float* __restrict__ P0, float* __restrict__ P1){
  __shared__ __align__(16) unsigned short Ql[64*256];   // frag-major Q tile
  __shared__ __align__(16) unsigned short Sl[64*264];   // [q][key] padded
  int tid = threadIdx.x;
  int blk = blockIdx.x;
  int qt = blk >> 3, combo = blk & 7;
  int b = combo >> 1, half = combo & 1;
  int q0 = qt*64;
  int lane = tid & 63, w = tid >> 6;
  int l31 = lane & 31, l5 = lane >> 5;
  float* P = half ? P1 : P0;

  int gq0 = b*128 + qt*2;
  {
    const uint4* src = (const uint4*)(Qf + (size_t)gq0*8192);
    uint4* dst = (uint4*)Ql;
#pragma unroll
    for (int it = 0; it < 4; ++it) dst[it*512 + tid] = src[it*512 + tid];
  }
  __syncthreads();

  f32x16 acc2[2] = {};
  int gk0 = b*128 + half*64 + w;
  const unsigned short* kb = Kf + (size_t)gk0*8192 + lane*8;
  const unsigned short* vb = Vf + ((size_t)((b*8 + w)*256 + half*128))*512 + lane*8;
  const unsigned short* qa0 = Ql + lane*8;
  const unsigned short* qa1 = Ql + 16*512 + lane*8;

  for (int kt = 0; kt < 8; ++kt){
    f32x16 a1[2] = {};
    const unsigned short* kbt = kb + (size_t)kt*8*8192;
    __builtin_amdgcn_s_setprio(1);
#pragma unroll
    for (int ks = 0; ks < 16; ++ks){
      short8 kf = *(const short8*)(kbt + ks*512);
      short8 q0v = *(const short8*)(qa0 + ks*512);
      short8 q1v = *(const short8*)(qa1 + ks*512);
      a1[0] = __builtin_amdgcn_mfma_f32_32x32x16_bf16(q0v, kf, a1[0], 0, 0, 0);
      a1[1] = __builtin_amdgcn_mfma_f32_32x32x16_bf16(q1v, kf, a1[1], 0, 0, 0);
    }
    __builtin_amdgcn_s_setprio(0);
    __syncthreads();     // B0
#pragma unroll
    for (int reg = 0; reg < 16; ++reg){
      int rloc = (reg & 3) + 8*(reg >> 2) + 4*l5;
      float x0 = a1[0][reg], x1 = a1[1][reg];
      Sl[rloc*264 + w*32 + l31]        = f2bf(fmaxf(x0, 0.3f*x0));
      Sl[(32 + rloc)*264 + w*32 + l31] = f2bf(fmaxf(x1, 0.3f*x1));
    }
    __syncthreads();     // B1
    const unsigned short* vbt = vb + (size_t)kt*16*512;
    __builtin_amdgcn_s_setprio(1);
#pragma unroll
    for (int kk = 0; kk < 16; ++kk){
      short8 vf = *(const short8*)(vbt + kk*512);
      short8 s0 = *(const short8*)(Sl + (     l31)*264 + kk*16 + l5*8);
      short8 s1 = *(const short8*)(Sl + (32 + l31)*264 + kk*16 + l5*8);
      acc2[0] = __builtin_amdgcn_mfma_f32_32x32x16_bf16(s0, vf, acc2[0], 0, 0, 0);
      acc2[1] = __builtin_amdgcn_mfma_f32_32x32x16_bf16(s1, vf, acc2[1], 0, 0, 0);
    }
    __builtin_amdgcn_s_setprio(0);
  }
#pragma unroll
  for (int c = 0; c < 2; ++c)
#pragma unroll
    for (int reg = 0; reg < 16; ++reg){
      int row = q0 + c*32 + (reg & 3) + 8*(reg >> 2) + 4*l5;
      P[((size_t)b*4096 + row)*256 + w*32 + l31] = acc2[c][reg];
    }
}

// ------------------------------------------------- partial reduce + BN stats
// 512 blocks x 32 rows, float4 path; f32 LDS pg-reduce, f64 atomics.
__global__ __launch_bounds__(256)
void k_red(const float* __restrict__ P0, const float* __restrict__ P1,
           float* __restrict__ yout, double* __restrict__ st){
  __shared__ float redS[4][256];
  __shared__ float redQ[4][256];
  int tid = threadIdx.x;
  int cg = (tid & 63)*4, pg = tid >> 6;
  int r0 = blockIdx.x*32;
  float s0=0,s1=0,s2=0,s3=0,q0=0,q1=0,q2=0,q3=0;
#pragma unroll
  for (int k = 0; k < 8; ++k){
    size_t idx = (size_t)(r0 + pg + k*4)*256 + cg;
    float4 a = *(const float4*)(P0 + idx);
    float4 b = *(const float4*)(P1 + idx);
    float4 v; v.x=a.x+b.x; v.y=a.y+b.y; v.z=a.z+b.z; v.w=a.w+b.w;
    *(float4*)(yout + idx) = v;
    s0 += v.x; q0 += v.x*v.x;
    s1 += v.y; q1 += v.y*v.y;
    s2 += v.z; q2 += v.z*v.z;
    s3 += v.w; q3 += v.w*v.w;
  }
  *(float4*)(&redS[pg][cg]) = make_float4(s0,s1,s2,s3);
  *(float4*)(&redQ[pg][cg]) = make_float4(q0,q1,q2,q3);
  __syncthreads();
  float s = redS[0][tid] + redS[1][tid] + redS[2][tid] + redS[3][tid];
  float q = redQ[0][tid] + redQ[1][tid] + redQ[2][tid] + redQ[3][tid];
  atomicAdd(&st[1536 + tid], (double)s);
  atomicAdd(&st[1792 + tid], (double)q);
}

// --------------------------------------------------------------- softmax
__global__ __launch_bounds__(256)
void k_soft1(const float* __restrict__ yout, const double* __restrict__ st,
             const float* __restrict__ g1, float* __restrict__ sums){
  __shared__ float redL[16][64];
  __shared__ float sA[64], sK[64];
  int tid = threadIdx.x;
  int chunk = blockIdx.x, ct = blockIdx.y, b = blockIdx.z;
  int cg = (tid & 15)*4, pg = tid >> 4;
  if (tid < 64){
    int cc = ct*64 + tid;
    double mu  = st[1536 + cc]*(1.0/NTOT);
    double var = st[1792 + cc]*(1.0/NTOT) - mu*mu;
    double a = g1[cc] / sqrt(var + EPS);
    sA[tid] = (float)a;
    sK[tid] = (float)(a*mu);
  }
  __syncthreads();
  float a0=sA[cg], a1=sA[cg+1], a2=sA[cg+2], a3=sA[cg+3];
  float K0=sK[cg], K1=sK[cg+1], K2=sK[cg+2], K3=sK[cg+3];
  const float* base = yout + ((size_t)b*4096 + chunk*256)*256 + ct*64 + cg;
  float s0=0,s1=0,s2=0,s3=0;
#pragma unroll
  for (int k = 0; k < 16; ++k){
    float4 v = *(const float4*)(base + (size_t)(pg + k*16)*256);
    s0 += __expf(v.x*a0 - K0);
    s1 += __expf(v.y*a1 - K1);
    s2 += __expf(v.z*a2 - K2);
    s3 += __expf(v.w*a3 - K3);
  }
  *(float4*)(&redL[pg][cg]) = make_float4(s0,s1,s2,s3);
  __syncthreads();
  if (tid < 64){
    float tot = 0.f;
#pragma unroll
    for (int p = 0; p < 16; ++p) tot += redL[p][tid];
    atomicAdd(&sums[b*256 + ct*64 + tid], tot);
  }
}

__global__ __launch_bounds__(256)
void k_soft2(const float* __restrict__ yout, const double* __restrict__ st,
             const float* __restrict__ g1, const float* __restrict__ sums,
             float* __restrict__ out){
  __shared__ float sA[64], sK[64], sR[64];
  int tid = threadIdx.x;
  int chunk = blockIdx.x, ct = blockIdx.y, b = blockIdx.z;
  int cg = (tid & 15)*4, pg = tid >> 4;
  if (tid < 64){
    int cc = ct*64 + tid;
    double mu  = st[1536 + cc]*(1.0/NTOT);
    double var = st[1792 + cc]*(1.0/NTOT) - mu*mu;
    double a = g1[cc] / sqrt(var + EPS);
    sA[tid] = (float)a;
    sK[tid] = (float)(a*mu);
    sR[tid] = 1.f / sums[b*256 + cc];
  }
  __syncthreads();
  float a0=sA[cg], a1=sA[cg+1], a2=sA[cg+2], a3=sA[cg+3];
  float K0=sK[cg], K1=sK[cg+1], K2=sK[cg+2], K3=sK[cg+3];
  float r0=sR[cg], r1=sR[cg+1], r2=sR[cg+2], r3=sR[cg+3];
  const float* base = yout + ((size_t)b*4096 + chunk*256)*256 + ct*64 + cg;
  float* obase = out + ((size_t)b*4096 + chunk*256)*256 + ct*64 + cg;
#pragma unroll
  for (int k = 0; k < 16; ++k){
    size_t off = (size_t)(pg + k*16)*256;
    float4 v = *(const float4*)(base + off);
    float4 o;
    o.x = __expf(v.x*a0 - K0) * r0;
    o.y = __expf(v.y*a1 - K1) * r1;
    o.z = __expf(v.z*a2 - K2) * r2;
    o.w = __expf(v.w*a3 - K3) * r3;
    *(float4*)(obase + off) = o;
  }
}

// ---------------------------------------------------------------------------
extern "C" void kernel_launch(void* const* d_in, const int* in_sizes, int n_in,
                              void* d_out, int out_size, void* d_ws, size_t ws_size,
                              hipStream_t stream){
  (void)in_sizes; (void)n_in; (void)out_size; (void)ws_size;
  const float* X  = (const float*)d_in[0];
  const float* Wq = (const float*)d_in[1];
  const float* gq = (const float*)d_in[2];
  const float* bq = (const float*)d_in[3];
  const float* Wk = (const float*)d_in[4];
  const float* gk = (const float*)d_in[5];
  const float* bk = (const float*)d_in[6];
  const float* Wv = (const float*)d_in[7];
  const float* gv = (const float*)d_in[8];
  const float* bv = (const float*)d_in[9];
  const float* g1 = (const float*)d_in[10];
  // d_in[11] = b1: cancels inside the spatial softmax

  char* ws = (char*)d_ws;
  double*         st   = (double*)ws;                        // 2048 f64 (16KB)
  float*          sums = (float*)(ws + 16384);               // 4KB
  unsigned short* Wt   = (unsigned short*)(ws + 26624);      // 768x256 bf16 -> ends 419840
  unsigned short* Xb   = (unsigned short*)(ws + 419840);     // 8MB -> ends 8808448
  unsigned short* YQK  = (unsigned short*)(ws + 8808448);    // 16MB bf16 frag-major -> 25585664
  unsigned short* Yv   = (unsigned short*)(ws + 25585664);   // 8MB bf16 row-major -> 33974272
  unsigned short* Kf   = (unsigned short*)(ws + 33974272);   // 8MB frag-major -> 42362880
  unsigned short* Vf   = (unsigned short*)(ws + 42362880);   // 8MB frag-major -> 50751488
  float*          P1   = (float*)(ws + 50751488);            // 16MB -> 67528704
  // overlays: Qf on Xb (dead after GEMM); P0 on YQK (dead after bn);
  // yout on Kf+Vf (dead after attn)
  unsigned short* Qf   = Xb;
  float*          P0   = (float*)(ws + 8808448);
  float*          yo   = (float*)(ws + 33974272);

  k_prep    <<<4864, 256, 0, stream>>>(X, Wq, Wk, Wv, Xb, Wt, (float*)st);
  k_qkv_gemm<<<768, 256, 0, stream>>>(Xb, Wt, YQK, Yv, st);
  k_bn      <<<5120, 256, 0, stream>>>(YQK, Yv, st, gq, bq, gk, bk, gv, bv, Qf, Kf, Vf);
  k_attn    <<<512, 512, 0, stream>>>(Qf, Kf, Vf, P0, P1);
  k_red     <<<512, 256, 0, stream>>>(P0, P1, yo, st);
  k_soft1   <<<dim3(16,4,4), 256, 0, stream>>>(yo, st, g1, sums);
  k_soft2   <<<dim3(16,4,4), 256, 0, stream>>>(yo, st, g1, sums, (float*)d_out);
}